// Round 1
// baseline (6347.030 us; speedup 1.0000x reference)
//
#include <hip/hip_runtime.h>

#define N_NODES 50000
#define N_EDGE  150000
#define N_GRAPH 200
#define DIM     320
#define EDI     15
#define EH      32
#define NBLK    3
#define NTYP    9
#define NPAD    51200   // per-type CSR stride (50 blocks of 1024)
#define BPT     50      // scan blocks per type
#define QLD     1000    // qkv row stride (993 used cols)

typedef unsigned short u16;
typedef unsigned int   u32;
typedef __bf16 bf16x8 __attribute__((ext_vector_type(8)));
typedef float  f32x4  __attribute__((ext_vector_type(4)));

__device__ __forceinline__ float b2f(u16 s) {
    u32 u = ((u32)s) << 16;
    return __builtin_bit_cast(float, u);
}
__device__ __forceinline__ float b2f_lo(u32 u) { return __builtin_bit_cast(float, u << 16); }
__device__ __forceinline__ float b2f_hi(u32 u) { return __builtin_bit_cast(float, u & 0xffff0000u); }
__device__ __forceinline__ u16 f2b(float f) {
    u32 u = __builtin_bit_cast(u32, f);
    u = (u + 0x7fffu + ((u >> 16) & 1u)) >> 16;
    return (u16)u;
}

// global -> LDS direct DMA, 16 B per lane. LDS dest = m0 + lane*16 (wave-uniform
// base), global src per-lane. CK-style m0 idiom; compiler can't track these in
// vmcnt, so every consumer path drains with an explicit asm s_waitcnt vmcnt(0).
__device__ __forceinline__ void gll16(const u16* g, u32 ldsAddr) {
    u32 m0v = (u32)__builtin_amdgcn_readfirstlane((int)ldsAddr);
    asm volatile("s_mov_b32 m0, %0\n\t"
                 "global_load_lds_dwordx4 %1, off"
                 :: "s"(m0v), "v"((unsigned long long)(size_t)g)
                 : "memory");
}

// ---------------------------------------------------------------------------
// bf16 MFMA GEMM — LDS-staged, double-buffered 2-phase pipeline (T3 minimum).
// Inputs pre-staged kq-major: element (k, m) at ((k>>3)*Stride + m)*8 + (k&7),
// which is exactly the linear lane order global_load_lds requires (64 lanes x
// 16 B contiguous per 8-k chunk). Tile 128x128, BK=32 (4 chunks), 4 waves of
// 64x64, LDS 2buf x (A 8KB + B 8KB) = 32 KB.
// mode 0: Cb=bf16 ; 1: Cf=f32 ; 2: Cf += f32
// ---------------------------------------------------------------------------
__global__ __launch_bounds__(256) void gemm_kernel(
    const u16* __restrict__ A, int Mstride,
    const u16* __restrict__ Bst, const float* __restrict__ bias,
    u16* __restrict__ Cb, float* __restrict__ Cf,
    int ldc, int out_cols, int M, int NP, int KQ, int mode)
{
    const int tid = threadIdx.x;
    const int wave = tid >> 6, lane = tid & 63;
    const int n0 = blockIdx.x * 128, m0 = blockIdx.y * 128;
    const int wm = (wave & 1) << 6, wn = (wave >> 1) << 6;
    const int lm = lane & 15, quad = lane >> 4;

    // [buf][A/B][chunk(4)][node(128)] of 16B slots
    __shared__ uint4 smem[2][2][512];
    const u32 ldsBase = (u32)(size_t)&smem[0][0][0];

    f32x4 acc[4][4] = {};
    const int nIter = KQ >> 2;   // K-steps of 32 (4 chunks of 8)

    // stage step s into buffer buf: per wave 2 A-units + 2 B-units
    // unit i (0..7): chunk=i>>1, node-half=(i&1)*64 ; wave w owns {w, w+4}
    auto stage = [&](int s, int buf) {
        const int c0 = s << 2;
        const u32 bufBase = ldsBase + (u32)buf * 16384u;
#pragma unroll
        for (int u = 0; u < 2; ++u) {
            const int i = wave + (u << 2);
            const int chunk = i >> 1, half = (i & 1) << 6;
            const u16* ga = A + ((size_t)(c0 + chunk) * Mstride + m0 + half + lane) * 8;
            gll16(ga, bufBase + (u32)i * 1024u);
            const u16* gb = Bst + ((size_t)(c0 + chunk) * NP + n0 + half + lane) * 8;
            gll16(gb, bufBase + 8192u + (u32)i * 1024u);
        }
    };

    stage(0, 0);
    asm volatile("s_waitcnt vmcnt(0)" ::: "memory");
    __syncthreads();

    int cur = 0;
    for (int s = 0; s < nIter; ++s) {
        if (s + 1 < nIter) stage(s + 1, cur ^ 1);   // prefetch next tile
        const uint4* aT = &smem[cur][0][0];
        const uint4* bT = &smem[cur][1][0];
        bf16x8 af[4], bfr[4];
#pragma unroll
        for (int mi = 0; mi < 4; ++mi)
            af[mi] = __builtin_bit_cast(bf16x8, aT[quad * 128 + wm + mi * 16 + lm]);
#pragma unroll
        for (int ni = 0; ni < 4; ++ni)
            bfr[ni] = __builtin_bit_cast(bf16x8, bT[quad * 128 + wn + ni * 16 + lm]);
#pragma unroll
        for (int mi = 0; mi < 4; ++mi)
#pragma unroll
            for (int ni = 0; ni < 4; ++ni)
                acc[mi][ni] = __builtin_amdgcn_mfma_f32_16x16x32_bf16(af[mi], bfr[ni], acc[mi][ni], 0, 0, 0);
        // drain the prefetch (untracked by compiler), then release buffers
        asm volatile("s_waitcnt vmcnt(0)" ::: "memory");
        __syncthreads();
        cur ^= 1;
    }

    // epilogue: C/D layout col=lane&15, row=quad*4+reg
#pragma unroll
    for (int mi = 0; mi < 4; ++mi) {
        int row = m0 + wm + mi * 16 + quad * 4;
#pragma unroll
        for (int ni = 0; ni < 4; ++ni) {
            int col = n0 + wn + ni * 16 + lm;
            float bv = bias ? bias[col] : 0.f;
#pragma unroll
            for (int r = 0; r < 4; ++r) {
                int rr = row + r;
                if (rr < M && col < out_cols) {
                    float v = acc[mi][ni][r] + bv;
                    size_t off = (size_t)rr * ldc + col;
                    if (mode == 0)      Cb[off] = f2b(v);
                    else if (mode == 1) Cf[off] = v;
                    else                Cf[off] += v;
                }
            }
        }
    }
}

// ---------------------------------------------------------------------------
// prep kernels
// ---------------------------------------------------------------------------
__global__ void k_convert_x(const float* __restrict__ x, u16* __restrict__ hb) {
    int i = blockIdx.x * 256 + threadIdx.x;
    if (i >= N_NODES * DIM) return;
    int node = i / DIM, c = i - node * DIM;
    hb[((size_t)(c >> 3) * N_NODES + node) * 8 + (c & 7)] = f2b(x[i]);
}

// Bst_qkv cols 0-959 from Wq|Wk|Wv, cols >=993 zero. Coalesced uint4 writes.
__global__ void k_prep_qkvW(const float* __restrict__ Wq, const float* __restrict__ Wk,
                            const float* __restrict__ Wv, u16* __restrict__ Bst) {
    int i = blockIdx.x * 256 + threadIdx.x;
    if (i >= 27 * 40 * 1024) return;
    int col = i & 1023, kq = (i >> 10) % 40, bt = i / (40 * 1024);
    if (col >= 960 && col < 993) return;  // ext cols written by k_prep_ext
    u16 tmp[8];
    if (col >= 993) {
#pragma unroll
        for (int r = 0; r < 8; ++r) tmp[r] = 0;
    } else {
        const float* W; int c;
        if (col < 320)      { W = Wq; c = col; }
        else if (col < 640) { W = Wk; c = col - 320; }
        else                { W = Wv; c = col - 640; }
#pragma unroll
        for (int r = 0; r < 8; ++r)
            tmp[r] = f2b(W[((size_t)bt * 320 + kq * 8 + r) * 320 + c]);
    }
    *(uint4*)(&Bst[(((size_t)bt * 40 + kq) * 1024 + col) * 8]) = *(uint4*)tmp;
}

// ext columns: 960+c = (Wq@We^T) c<32 ; 992 = Wq@be ; plus bias from bq
__global__ __launch_bounds__(256) void k_prep_ext(
    const float* __restrict__ Wq, const float* __restrict__ bq,
    const float* __restrict__ We, const float* __restrict__ be,
    u16* __restrict__ Bst, float* __restrict__ biasQkv)
{
    __shared__ float WeL[33 * 321];
    int bt = blockIdx.x, kt = blockIdx.y;  // kt 0..10
    for (int i = threadIdx.x; i < 33 * 320; i += 256) {
        int r = i / 320, d = i - r * 320;
        WeL[r * 321 + d] = (r < 32) ? We[((size_t)bt * 32 + r) * 320 + d]
                                    : be[(size_t)bt * 320 + d];
    }
    __syncthreads();
    if (kt < 10) {
        int k  = kt * 32 + (threadIdx.x >> 3);
        int ct = threadIdx.x & 7;
        const float* wq = Wq + ((size_t)bt * 320 + k) * 320;
        float dot[5] = {0.f, 0.f, 0.f, 0.f, 0.f};
        for (int d = 0; d < 320; ++d) {
            float w = wq[d];
            dot[0] += w * WeL[ct * 321 + d];
            dot[1] += w * WeL[(ct + 8) * 321 + d];
            dot[2] += w * WeL[(ct + 16) * 321 + d];
            dot[3] += w * WeL[(ct + 24) * 321 + d];
            dot[4] += w * WeL[32 * 321 + d];
        }
#pragma unroll
        for (int u = 0; u < 4; ++u)
            Bst[(((size_t)bt * 40 + (k >> 3)) * 1024 + 960 + ct + u * 8) * 8 + (k & 7)] = f2b(dot[u]);
        if (ct == 0)
            Bst[(((size_t)bt * 40 + (k >> 3)) * 1024 + 992) * 8 + (k & 7)] = f2b(dot[4]);
    } else {
        int c = threadIdx.x;
        if (c < 33) {
            const float* b = bq + (size_t)bt * 320;
            float s = 0.f;
            for (int d = 0; d < 320; ++d) s += b[d] * WeL[c * 321 + d];
            biasQkv[bt * 1024 + 960 + c] = s;
        }
    }
}

__global__ void k_prep_qkvB(const float* __restrict__ bq, const float* __restrict__ bk,
                            const float* __restrict__ bv, float* __restrict__ bias) {
    int i = blockIdx.x * 256 + threadIdx.x;
    if (i >= 27 * 1024) return;
    int col = i & 1023, bt = i >> 10;
    float v;
    if (col < 320)       v = bq[bt * 320 + col];
    else if (col < 640)  v = bk[bt * 320 + col - 320];
    else if (col < 960)  v = bv[bt * 320 + col - 640];
    else if (col >= 993) v = 0.f;
    else return;  // ext
    bias[i] = v;
}

__global__ void k_prep_skipW(const float* __restrict__ Ws, u16* __restrict__ Bst) {
    int i = blockIdx.x * 256 + threadIdx.x;
    if (i >= 3 * 320 * 384) return;
    int col = i % 384, k = (i / 384) % 320, b = i / (384 * 320);
    float v = 0.f;
    if (col < 320)
        for (int t = 0; t < 9; ++t)
            v += Ws[((size_t)(b * 9 + t) * 320 + k) * 320 + col];
    Bst[(((size_t)b * 40 + (k >> 3)) * 384 + col) * 8 + (k & 7)] = f2b(v);
}
__global__ void k_prep_skipB(const float* __restrict__ bs, float* __restrict__ bias) {
    int i = blockIdx.x * 256 + threadIdx.x;
    if (i >= 3 * 384) return;
    int col = i % 384, b = i / 384;
    float v = 0.f;
    if (col < 320)
        for (int t = 0; t < 9; ++t) v += bs[(b * 9 + t) * 320 + col];
    bias[i] = v;
}

// We_all for batched s-GEMM: K rows k=t*34+j ; j<32 -> We[b*9+t][j], j==32 -> be,
// j==33 / k>=306 / col>=320 -> 0.  Layout [3][40][384][8].
__global__ void k_prep_sWe(const float* __restrict__ We, const float* __restrict__ be,
                           u16* __restrict__ Bst) {
    int i = blockIdx.x * 256 + threadIdx.x;
    if (i >= 3 * 40 * 384) return;
    int col = i % 384, kq = (i / 384) % 40, b = i / (384 * 40);
    u16 tmp[8];
#pragma unroll
    for (int r = 0; r < 8; ++r) {
        int k = kq * 8 + r;
        float v = 0.f;
        if (col < 320 && k < 306) {
            int t = k / 34, j = k - t * 34;
            int bt = b * 9 + t;
            if (j < 32)       v = We[((size_t)bt * 32 + j) * 320 + col];
            else if (j == 32) v = be[(size_t)bt * 320 + col];
        }
        tmp[r] = f2b(v);
    }
    *(uint4*)(&Bst[(((size_t)b * 40 + kq) * 384 + col) * 8]) = *(uint4*)tmp;
}

__global__ void k_prep_w1W(const float* __restrict__ W1, u16* __restrict__ Bst) {
    int i = blockIdx.x * 256 + threadIdx.x;
    if (i >= 320 * 128) return;
    int col = i & 127, k = i >> 7;
    float v = 0.f;
    if (col < 32)      v = W1[(size_t)k * 32 + col];
    else if (col < 64) v = W1[(size_t)(320 + k) * 32 + (col - 32)];
    Bst[((size_t)(k >> 3) * 128 + col) * 8 + (k & 7)] = f2b(v);
}

// ---------------------------------------------------------------------------
// CSR build
// ---------------------------------------------------------------------------
__global__ void k_csr_zero(int* __restrict__ cnt) {
    int i = blockIdx.x * 256 + threadIdx.x;
    if (i < NTYP * NPAD) cnt[i] = 0;
}
__global__ void k_csr_count(const int* __restrict__ eidx, int* __restrict__ cnt) {
    int i = blockIdx.x * 256 + threadIdx.x;
    if (i >= NTYP * N_EDGE) return;
    int t = i / N_EDGE, e = i - t * N_EDGE;
    int dst = eidx[(size_t)(t * 2 + 1) * N_EDGE + e];
    atomicAdd(&cnt[t * NPAD + dst], 1);
}
__global__ __launch_bounds__(1024) void k_csr_scan1(const int* __restrict__ cnt,
                                                    int* __restrict__ rowStart,
                                                    int* __restrict__ blockSum) {
    __shared__ int tmp[1024];
    int t = blockIdx.y, blk = blockIdx.x, tid = threadIdx.x;
    int idx = t * NPAD + blk * 1024 + tid;
    int v = cnt[idx];
    tmp[tid] = v;
    __syncthreads();
    for (int off = 1; off < 1024; off <<= 1) {
        int x = (tid >= off) ? tmp[tid - off] : 0;
        __syncthreads();
        tmp[tid] += x;
        __syncthreads();
    }
    rowStart[idx] = tmp[tid] - v;
    if (tid == 1023) blockSum[t * 64 + blk] = tmp[tid];
}
__global__ void k_csr_scan2(int* __restrict__ blockSum) {
    int t = threadIdx.x;
    if (t >= NTYP) return;
    int run = 0;
    for (int b = 0; b < BPT; ++b) {
        int v = blockSum[t * 64 + b];
        blockSum[t * 64 + b] = run;
        run += v;
    }
}
__global__ void k_csr_scan3(int* __restrict__ rowStart, const int* __restrict__ blockSum,
                            int* __restrict__ cursor) {
    int i = blockIdx.x * 256 + threadIdx.x;
    if (i >= NTYP * NPAD) return;
    int t = i / NPAD, n = i - t * NPAD;
    int v = rowStart[i] + blockSum[t * 64 + (n >> 10)];
    rowStart[i] = v;
    cursor[i] = v;
}
__global__ void k_csr_scatter(const int* __restrict__ eidx, int* __restrict__ cursor,
                              u16* __restrict__ sSrc, int* __restrict__ sEid) {
    int i = blockIdx.x * 256 + threadIdx.x;
    if (i >= NTYP * N_EDGE) return;
    int t = i / N_EDGE, e = i - t * N_EDGE;
    int src = eidx[(size_t)(t * 2) * N_EDGE + e];
    int dst = eidx[(size_t)(t * 2 + 1) * N_EDGE + e];
    int pos = atomicAdd(&cursor[t * NPAD + dst], 1);
    sSrc[(size_t)t * N_EDGE + pos] = (u16)src;
    sEid[(size_t)t * N_EDGE + pos] = e;
}

// ---------------------------------------------------------------------------
// Edge MLP for one type t
// ---------------------------------------------------------------------------
__global__ __launch_bounds__(256) void k_edge_mlp(
    const u16* __restrict__ Anodes, const int* __restrict__ eidx,
    const float* __restrict__ eattr, const float* __restrict__ W1,
    const float* __restrict__ b1, const float* __restrict__ W2,
    const float* __restrict__ b2, u16* __restrict__ outEa, int t)
{
    __shared__ float w1c[EDI][EH];
    __shared__ float w2s[EH][EH];
    __shared__ float b1s[EH], b2s[EH];
    int tid = threadIdx.x;
    for (int i = tid; i < EDI * EH; i += 256) w1c[i / EH][i % EH] = W1[(640 + i / EH) * EH + (i % EH)];
    for (int i = tid; i < EH * EH; i += 256) w2s[i / EH][i % EH] = W2[i];
    if (tid < EH) { b1s[tid] = b1[tid]; b2s[tid] = b2[tid]; }
    __syncthreads();

    int e = blockIdx.x * 256 + tid;
    if (e >= N_EDGE) return;
    int src = eidx[(size_t)(t * 2) * N_EDGE + e];
    int dst = eidx[(size_t)(t * 2 + 1) * N_EDGE + e];
    const float* eat = eattr + ((size_t)t * N_EDGE + e) * EDI;
    const u16* a1 = Anodes + (size_t)src * 64;
    const u16* a2 = Anodes + (size_t)dst * 64 + 32;

    float h1[EH];
#pragma unroll
    for (int j = 0; j < EH; ++j) h1[j] = b2f(a1[j]) + b2f(a2[j]) + b1s[j];
    for (int i = 0; i < EDI; ++i) {
        float v = eat[i];
#pragma unroll
        for (int j = 0; j < EH; ++j) h1[j] += v * w1c[i][j];
    }
#pragma unroll
    for (int j = 0; j < EH; ++j) h1[j] = h1[j] > 0.f ? h1[j] : 0.01f * h1[j];

    u16* orow = outEa + (size_t)e * EH;
    for (int j = 0; j < EH; ++j) {
        float o = b2s[j];
#pragma unroll
        for (int i = 0; i < EH; ++i) o += h1[i] * w2s[i][j];
        orow[j] = f2b(o);
    }
}

// ---------------------------------------------------------------------------
// Attention: one wave per dst node, CSR range, online softmax, unroll x2.
// Lane layout: lane l owns cols [4l..4l+3] (uint2 load) + col 256+l -> 5
// vectorized loads per edge (was 11 scalar u16). acc RMW is float4/lane.
// Epilogue also writes s row (32 vals + flag) into kq-major sST.
// ---------------------------------------------------------------------------
__global__ __launch_bounds__(256) void k_attn(
    const u16* __restrict__ qkv, const int* __restrict__ rowStart,
    const u16* __restrict__ sSrc, const int* __restrict__ sEid,
    const u16* __restrict__ ea, float* __restrict__ acc,
    u16* __restrict__ sST, int t34)
{
    int wave = threadIdx.x >> 6, lane = threadIdx.x & 63;
    int n = blockIdx.x * 4 + wave;
    if (n >= N_NODES) return;
    int eb = rowStart[n], ee = rowStart[n + 1];
    if (eb == ee) return;  // empty: acc untouched, s row stays zero

    const u16* qrow = qkv + (size_t)n * QLD;
    uint2 qv = *(const uint2*)(qrow + 4 * lane);
    float q40 = b2f_lo(qv.x), q41 = b2f_hi(qv.x);
    float q42 = b2f_lo(qv.y), q43 = b2f_hi(qv.y);
    float q1 = b2f(qrow[256 + lane]);
    float qwl = (lane < 33) ? b2f(qrow[960 + lane]) : 0.f;
    float qwbe = __shfl(qwl, 32, 64);
    float qw = (lane < 32) ? qwl : 0.f;
    const float RS = 0.05590169943749474f;  // 1/sqrt(320)

    float m = -INFINITY, l = 0.f, as = 0.f;
    float av0 = 0.f, av1 = 0.f, av2 = 0.f, av3 = 0.f, avt = 0.f;

    int ei = eb;
    for (; ei + 2 <= ee; ei += 2) {
        int s0 = sSrc[ei], s1 = sSrc[ei + 1];
        int id0 = sEid[ei], id1 = sEid[ei + 1];
        const u16* kr0 = qkv + (size_t)s0 * QLD + 320;
        const u16* kr1 = qkv + (size_t)s1 * QLD + 320;
        uint2 k0v = *(const uint2*)(kr0 + 4 * lane);
        uint2 k1v = *(const uint2*)(kr1 + 4 * lane);
        float k0t = b2f(kr0[256 + lane]);
        float k1t = b2f(kr1[256 + lane]);
        float ea0 = (lane < 32) ? b2f(ea[(size_t)id0 * 32 + lane]) : 0.f;
        float ea1 = (lane < 32) ? b2f(ea[(size_t)id1 * 32 + lane]) : 0.f;
        float d0 = qw * ea0 + q1 * k0t
                 + q40 * b2f_lo(k0v.x) + q41 * b2f_hi(k0v.x)
                 + q42 * b2f_lo(k0v.y) + q43 * b2f_hi(k0v.y);
        float d1 = qw * ea1 + q1 * k1t
                 + q40 * b2f_lo(k1v.x) + q41 * b2f_hi(k1v.x)
                 + q42 * b2f_lo(k1v.y) + q43 * b2f_hi(k1v.y);
#pragma unroll
        for (int off = 32; off > 0; off >>= 1) {
            d0 += __shfl_xor(d0, off, 64);
            d1 += __shfl_xor(d1, off, 64);
        }
        float a0 = (d0 + qwbe) * RS, a1 = (d1 + qwbe) * RS;
        float mn = fmaxf(m, fmaxf(a0, a1));
        float sc = __expf(m - mn);
        float p0 = __expf(a0 - mn), p1 = __expf(a1 - mn);
        l = l * sc + p0 + p1;
        const u16* vr0 = kr0 + 320;
        const u16* vr1 = kr1 + 320;
        uint2 v0v = *(const uint2*)(vr0 + 4 * lane);
        uint2 v1v = *(const uint2*)(vr1 + 4 * lane);
        float v0t = b2f(vr0[256 + lane]), v1t = b2f(vr1[256 + lane]);
        av0 = av0 * sc + p0 * b2f_lo(v0v.x) + p1 * b2f_lo(v1v.x);
        av1 = av1 * sc + p0 * b2f_hi(v0v.x) + p1 * b2f_hi(v1v.x);
        av2 = av2 * sc + p0 * b2f_lo(v0v.y) + p1 * b2f_lo(v1v.y);
        av3 = av3 * sc + p0 * b2f_hi(v0v.y) + p1 * b2f_hi(v1v.y);
        avt = avt * sc + p0 * v0t + p1 * v1t;
        as = as * sc + p0 * ea0 + p1 * ea1;
        m = mn;
    }
    if (ei < ee) {
        int s0 = sSrc[ei];
        int id0 = sEid[ei];
        const u16* kr0 = qkv + (size_t)s0 * QLD + 320;
        uint2 k0v = *(const uint2*)(kr0 + 4 * lane);
        float k0t = b2f(kr0[256 + lane]);
        float ea0 = (lane < 32) ? b2f(ea[(size_t)id0 * 32 + lane]) : 0.f;
        float d0 = qw * ea0 + q1 * k0t
                 + q40 * b2f_lo(k0v.x) + q41 * b2f_hi(k0v.x)
                 + q42 * b2f_lo(k0v.y) + q43 * b2f_hi(k0v.y);
#pragma unroll
        for (int off = 32; off > 0; off >>= 1) d0 += __shfl_xor(d0, off, 64);
        float a0 = (d0 + qwbe) * RS;
        float mn = fmaxf(m, a0);
        float sc = __expf(m - mn), p0 = __expf(a0 - mn);
        l = l * sc + p0;
        const u16* vr0 = kr0 + 320;
        uint2 v0v = *(const uint2*)(vr0 + 4 * lane);
        float v0t = b2f(vr0[256 + lane]);
        av0 = av0 * sc + p0 * b2f_lo(v0v.x);
        av1 = av1 * sc + p0 * b2f_hi(v0v.x);
        av2 = av2 * sc + p0 * b2f_lo(v0v.y);
        av3 = av3 * sc + p0 * b2f_hi(v0v.y);
        avt = avt * sc + p0 * v0t;
        as = as * sc + p0 * ea0;
    }

    float inv = 1.f / l;
    float* arow = acc + (size_t)n * DIM;
    f32x4 pa = *(const f32x4*)(arow + 4 * lane);
    pa[0] += av0 * inv; pa[1] += av1 * inv;
    pa[2] += av2 * inv; pa[3] += av3 * inv;
    *(f32x4*)(arow + 4 * lane) = pa;
    arow[256 + lane] += avt * inv;
    if (lane < 33) {
        int k = t34 + lane;
        float sv = (lane < 32) ? as * inv : 1.f;  // flag multiplies be row
        sST[((size_t)(k >> 3) * N_NODES + n) * 8 + (k & 7)] = f2b(sv);
    }
}

// ---------------------------------------------------------------------------
// Post: x_ = lrelu(acc/9); graph layernorm; h = 0.5*(h + x_) (h kq-major bf16)
// ---------------------------------------------------------------------------
__device__ __forceinline__ int lowerb(const int* a, int n, int v) {
    int lo = 0, hi = n;
    while (lo < hi) { int mid = (lo + hi) >> 1; if (a[mid] < v) lo = mid + 1; else hi = mid; }
    return lo;
}

__global__ __launch_bounds__(1024) void k_post(
    const float* __restrict__ acc, u16* __restrict__ hb,
    const int* __restrict__ batch, const float* __restrict__ gamma,
    const float* __restrict__ beta)
{
    int g = blockIdx.x;
    int start = lowerb(batch, N_NODES, g);
    int end   = lowerb(batch, N_NODES, g + 1);
    int cnt = end - start;
    if (cnt == 0) return;
    int i0 = start * DIM, i1 = end * DIM;

    float s = 0.f, ss = 0.f;
    for (int i = i0 + threadIdx.x; i < i1; i += 1024) {
        float v = acc[i] * (1.f / 9.f);
        v = v > 0.f ? v : 0.01f * v;
        s += v; ss += v * v;
    }
    __shared__ float rs[16], rss[16];
#pragma unroll
    for (int off = 32; off > 0; off >>= 1) { s += __shfl_xor(s, off, 64); ss += __shfl_xor(ss, off, 64); }
    int wave = threadIdx.x >> 6, lane = threadIdx.x & 63;
    if (lane == 0) { rs[wave] = s; rss[wave] = ss; }
    __syncthreads();
    if (threadIdx.x == 0) {
        float S = 0.f, SS = 0.f;
        for (int w = 0; w < 16; ++w) { S += rs[w]; SS += rss[w]; }
        float norm = (float)cnt * DIM;
        float mean = S / norm;
        float var = SS / norm - mean * mean;
        rs[0] = mean;
        rss[0] = rsqrtf(var + 1e-5f);
    }
    __syncthreads();
    float mean = rs[0], rsig = rss[0];
    for (int i = i0 + threadIdx.x; i < i1; i += 1024) {
        float v = acc[i] * (1.f / 9.f);
        v = v > 0.f ? v : 0.01f * v;
        int node = i / DIM, c = i - node * DIM;
        float o = (v - mean) * rsig * gamma[c] + beta[c];
        size_t hidx = ((size_t)(c >> 3) * N_NODES + node) * 8 + (c & 7);
        hb[hidx] = f2b(0.5f * (b2f(hb[hidx]) + o));
    }
}

__global__ __launch_bounds__(320) void k_maxpool(
    const u16* __restrict__ hb, const int* __restrict__ batch, float* __restrict__ out)
{
    int g = blockIdx.x, c = threadIdx.x;
    int start = lowerb(batch, N_NODES, g);
    int end   = lowerb(batch, N_NODES, g + 1);
    size_t base = (size_t)(c >> 3) * N_NODES * 8 + (c & 7);
    float m = -INFINITY;
    for (int n = start; n < end; ++n) m = fmaxf(m, b2f(hb[base + (size_t)n * 8]));
    out[(size_t)g * DIM + c] = m;
}

// ---------------------------------------------------------------------------
extern "C" void kernel_launch(void* const* d_in, const int* in_sizes, int n_in,
                              void* d_out, int out_size, void* d_ws, size_t ws_size,
                              hipStream_t stream)
{
    (void)in_sizes; (void)n_in; (void)out_size;
    const float* x     = (const float*)d_in[0];
    const int*   batch = (const int*)d_in[1];
    const int*   eidx  = (const int*)d_in[2];
    const float* eattr = (const float*)d_in[3];
    const float* W1 = (const float*)d_in[4];
    const float* b1 = (const float*)d_in[5];
    const float* W2 = (const float*)d_in[6];
    const float* b2 = (const float*)d_in[7];
    const float* Wq = (const float*)d_in[8];
    const float* bq = (const float*)d_in[9];
    const float* Wk = (const float*)d_in[10];
    const float* bk = (const float*)d_in[11];
    const float* Wv = (const float*)d_in[12];
    const float* bv = (const float*)d_in[13];
    const float* We = (const float*)d_in[14];
    const float* be = (const float*)d_in[15];
    const float* Ws = (const float*)d_in[16];
    const float* bs = (const float*)d_in[17];
    const float* gamma = (const float*)d_in[18];
    const float* beta  = (const float*)d_in[19];
    float* out = (float*)d_out;

    char* base = (char*)d_ws;
    size_t off = 0;
    auto carve = [&](size_t bytes) -> char* {
        char* r = base + off;
        off += (bytes + 255) & ~(size_t)255;
        return r;
    };
    u16*   hbKq    = (u16*)  carve((size_t)40 * N_NODES * 8 * 2 + 1024);  // 32 MB
    float* acc     = (float*)carve((size_t)N_NODES * DIM * 4);            // 64 MB
    u16*   qkv     = (u16*)  carve((size_t)N_NODES * QLD * 2);            // 100 MB
    u16*   sST     = (u16*)  carve((size_t)40 * N_NODES * 8 * 2 + 1024);  // 32 MB
    u16*   Anodes  = (u16*)  carve((size_t)N_NODES * 64 * 2);             // 6.4 MB
    u16*   BstQkv  = (u16*)  carve((size_t)27 * 40 * 1024 * 8 * 2);       // 17.7 MB
    float* biasQkv = (float*)carve((size_t)27 * 1024 * 4);
    u16*   BstSkip = (u16*)  carve((size_t)3 * 40 * 384 * 8 * 2);
    float* biasSkip= (float*)carve((size_t)3 * 384 * 4);
    u16*   BstSWe  = (u16*)  carve((size_t)3 * 40 * 384 * 8 * 2);
    u16*   BstW1   = (u16*)  carve((size_t)40 * 128 * 8 * 2);
    int*   cnt     = (int*)  carve((size_t)NTYP * NPAD * 4);
    int*   rowStart= (int*)  carve((size_t)NTYP * NPAD * 4);
    int*   blockSum= (int*)  carve((size_t)NTYP * 64 * 4);
    u16*   sSrc    = (u16*)  carve((size_t)NTYP * N_EDGE * 2);
    int*   sEid    = (int*)  carve((size_t)NTYP * N_EDGE * 4);
    size_t fixed = off;
    size_t bigBytes   = (size_t)NTYP * N_EDGE * EH * 2;
    size_t smallBytes = (size_t)N_EDGE * EH * 2;
    int bigEa = (ws_size >= fixed + bigBytes + (1u << 20)) ? 1 : 0;
    u16* newEa = (u16*)carve(bigEa ? bigBytes : smallBytes);

    // prep
    k_convert_x<<<(N_NODES * DIM + 255) / 256, 256, 0, stream>>>(x, hbKq);
    k_prep_qkvW<<<(27 * 40 * 1024 + 255) / 256, 256, 0, stream>>>(Wq, Wk, Wv, BstQkv);
    k_prep_ext<<<dim3(27, 11), 256, 0, stream>>>(Wq, bq, We, be, BstQkv, biasQkv);
    k_prep_qkvB<<<(27 * 1024 + 255) / 256, 256, 0, stream>>>(bq, bk, bv, biasQkv);
    k_prep_skipW<<<(3 * 320 * 384 + 255) / 256, 256, 0, stream>>>(Ws, BstSkip);
    k_prep_skipB<<<(3 * 384 + 255) / 256, 256, 0, stream>>>(bs, biasSkip);
    k_prep_sWe<<<(3 * 40 * 384 + 255) / 256, 256, 0, stream>>>(We, be, BstSWe);
    k_prep_w1W<<<(320 * 128 + 255) / 256, 256, 0, stream>>>(W1, BstW1);

    // CSR
    k_csr_zero<<<(NTYP * NPAD + 255) / 256, 256, 0, stream>>>(cnt);
    k_csr_count<<<(NTYP * N_EDGE + 255) / 256, 256, 0, stream>>>(eidx, cnt);
    k_csr_scan1<<<dim3(BPT, NTYP), 1024, 0, stream>>>(cnt, rowStart, blockSum);
    k_csr_scan2<<<1, 64, 0, stream>>>(blockSum);
    k_csr_scan3<<<(NTYP * NPAD + 255) / 256, 256, 0, stream>>>(rowStart, blockSum, cnt);
    k_csr_scatter<<<(NTYP * N_EDGE + 255) / 256, 256, 0, stream>>>(eidx, cnt, sSrc, sEid);

    const int mt = (N_NODES + 127) / 128;  // 391
    const int et = (N_EDGE + 255) / 256;
    // Anodes = x @ [W1a|W1b]
    gemm_kernel<<<dim3(1, mt), 256, 0, stream>>>(hbKq, N_NODES, BstW1, nullptr,
                                                 Anodes, nullptr, 64, 64, N_NODES, 128, 40, 0);
    if (bigEa) {
        for (int t = 0; t < NTYP; ++t)
            k_edge_mlp<<<dim3(et), 256, 0, stream>>>(
                Anodes, eidx, eattr, W1, b1, W2, b2, newEa + (size_t)t * N_EDGE * EH, t);
    }

    for (int b = 0; b < NBLK; ++b) {
        // acc = h @ sum_t(Ws) + sum_t(bs)
        gemm_kernel<<<dim3(3, mt), 256, 0, stream>>>(
            hbKq, N_NODES, BstSkip + (size_t)b * 40 * 384 * 8, biasSkip + b * 384,
            nullptr, acc, DIM, DIM, N_NODES, 384, 40, 1);
        hipMemsetAsync(sST, 0, (size_t)40 * N_NODES * 8 * 2, stream);
        for (int t = 0; t < NTYP; ++t) {
            int bt = b * NTYP + t;
            u16* eaT = bigEa ? (newEa + (size_t)t * N_EDGE * EH) : newEa;
            if (!bigEa)
                k_edge_mlp<<<dim3(et), 256, 0, stream>>>(
                    Anodes, eidx, eattr, W1, b1, W2, b2, eaT, t);
            gemm_kernel<<<dim3(8, mt), 256, 0, stream>>>(
                hbKq, N_NODES, BstQkv + (size_t)bt * 40 * 1024 * 8, biasQkv + bt * 1024,
                qkv, nullptr, QLD, 993, N_NODES, 1024, 40, 0);
            k_attn<<<dim3((N_NODES + 3) / 4), 256, 0, stream>>>(
                qkv, rowStart + t * NPAD, sSrc + (size_t)t * N_EDGE, sEid + (size_t)t * N_EDGE,
                eaT, acc, sST, t * 34);
        }
        // acc += s_all @ [We;be]_all   (batched over 9 types, K=306 padded 320)
        gemm_kernel<<<dim3(3, mt), 256, 0, stream>>>(
            sST, N_NODES, BstSWe + (size_t)b * 40 * 384 * 8, nullptr,
            nullptr, acc, DIM, DIM, N_NODES, 384, 40, 2);
        k_post<<<N_GRAPH, 1024, 0, stream>>>(acc, hbKq, batch,
                                             gamma + b * DIM, beta + b * DIM);
    }
    k_maxpool<<<N_GRAPH, 320, 0, stream>>>(hbKq, batch, out);
}

// Round 2
// 5767.566 us; speedup vs baseline: 1.1005x; 1.1005x over previous
//
#include <hip/hip_runtime.h>

#define N_NODES 50000
#define N_EDGE  150000
#define N_GRAPH 200
#define DIM     320
#define EDI     15
#define EH      32
#define NBLK    3
#define NTYP    9
#define NPAD    51200   // per-type CSR stride (50 blocks of 1024)
#define BPT     50      // scan blocks per type
#define QLD     676     // qkv' row stride (673 used cols), multiple of 4
#define QCOLS   673     // q''(0-319) | v(320-639) | qw(640-671) | qwbe(672)
#define NPQ     768     // qkv' GEMM N padded to 6 tiles of 128

typedef unsigned short u16;
typedef unsigned int   u32;
typedef __bf16 bf16x8 __attribute__((ext_vector_type(8)));
typedef float  f32x4  __attribute__((ext_vector_type(4)));

__device__ __forceinline__ float b2f(u16 s) {
    u32 u = ((u32)s) << 16;
    return __builtin_bit_cast(float, u);
}
__device__ __forceinline__ float b2f_lo(u32 u) { return __builtin_bit_cast(float, u << 16); }
__device__ __forceinline__ float b2f_hi(u32 u) { return __builtin_bit_cast(float, u & 0xffff0000u); }
__device__ __forceinline__ u16 f2b(float f) {
    u32 u = __builtin_bit_cast(u32, f);
    u = (u + 0x7fffu + ((u >> 16) & 1u)) >> 16;
    return (u16)u;
}

// global -> LDS direct DMA, 16 B per lane. LDS dest = m0 + lane*16 (wave-uniform
// base), global src per-lane. Untracked by compiler => explicit vmcnt drains.
__device__ __forceinline__ void gll16(const u16* g, u32 ldsAddr) {
    u32 m0v = (u32)__builtin_amdgcn_readfirstlane((int)ldsAddr);
    asm volatile("s_mov_b32 m0, %0\n\t"
                 "global_load_lds_dwordx4 %1, off"
                 :: "s"(m0v), "v"((unsigned long long)(size_t)g)
                 : "memory");
}

// ---------------------------------------------------------------------------
// bf16 MFMA GEMM — LDS-staged double-buffered, with T1 XCD-aware block swizzle
// (m204 bijective remap): consecutive dispatch ids land on different XCDs, so
// map each XCD to a CONTIGUOUS logical range => the 8/6/3 col-tiles sharing an
// A row-panel run on ONE XCD's L2 (fixes the 4x A-refetch seen in FETCH_SIZE).
// Inputs pre-staged kq-major: element (k, m) at ((k>>3)*Stride + m)*8 + (k&7).
// Tile 128x128, BK=32, 4 waves of 64x64. mode 0: Cb=bf16 ; 1: Cf=f32 ; 2: +=
// ---------------------------------------------------------------------------
__global__ __launch_bounds__(256) void gemm_kernel(
    const u16* __restrict__ A, int Mstride,
    const u16* __restrict__ Bst, const float* __restrict__ bias,
    u16* __restrict__ Cb, float* __restrict__ Cf,
    int ldc, int out_cols, int M, int NP, int KQ, int mode)
{
    const int tid = threadIdx.x;
    const int wave = tid >> 6, lane = tid & 63;

    // XCD swizzle: dispatch flat -> logical swz, XCD x gets contiguous ids
    const int nwg = gridDim.x * gridDim.y;
    const int flat = blockIdx.y * gridDim.x + blockIdx.x;
    const int qq = nwg >> 3, rr = nwg & 7;
    const int xcd = flat & 7, loc = flat >> 3;
    const int swz = (xcd < rr ? xcd * (qq + 1) : rr * (qq + 1) + (xcd - rr) * qq) + loc;
    const int n0 = (swz % gridDim.x) * 128, m0 = (swz / gridDim.x) * 128;

    const int wm = (wave & 1) << 6, wn = (wave >> 1) << 6;
    const int lm = lane & 15, quad = lane >> 4;

    // [buf][A/B][chunk(4)][node(128)] of 16B slots
    __shared__ uint4 smem[2][2][512];
    const u32 ldsBase = (u32)(size_t)&smem[0][0][0];

    f32x4 acc[4][4] = {};
    const int nIter = KQ >> 2;   // K-steps of 32 (4 chunks of 8)

    auto stage = [&](int s, int buf) {
        const int c0 = s << 2;
        const u32 bufBase = ldsBase + (u32)buf * 16384u;
#pragma unroll
        for (int u = 0; u < 2; ++u) {
            const int i = wave + (u << 2);
            const int chunk = i >> 1, half = (i & 1) << 6;
            const u16* ga = A + ((size_t)(c0 + chunk) * Mstride + m0 + half + lane) * 8;
            gll16(ga, bufBase + (u32)i * 1024u);
            const u16* gb = Bst + ((size_t)(c0 + chunk) * NP + n0 + half + lane) * 8;
            gll16(gb, bufBase + 8192u + (u32)i * 1024u);
        }
    };

    stage(0, 0);
    asm volatile("s_waitcnt vmcnt(0)" ::: "memory");
    __syncthreads();

    int cur = 0;
    for (int s = 0; s < nIter; ++s) {
        if (s + 1 < nIter) stage(s + 1, cur ^ 1);   // prefetch next tile
        const uint4* aT = &smem[cur][0][0];
        const uint4* bT = &smem[cur][1][0];
        bf16x8 af[4], bfr[4];
#pragma unroll
        for (int mi = 0; mi < 4; ++mi)
            af[mi] = __builtin_bit_cast(bf16x8, aT[quad * 128 + wm + mi * 16 + lm]);
#pragma unroll
        for (int ni = 0; ni < 4; ++ni)
            bfr[ni] = __builtin_bit_cast(bf16x8, bT[quad * 128 + wn + ni * 16 + lm]);
#pragma unroll
        for (int mi = 0; mi < 4; ++mi)
#pragma unroll
            for (int ni = 0; ni < 4; ++ni)
                acc[mi][ni] = __builtin_amdgcn_mfma_f32_16x16x32_bf16(af[mi], bfr[ni], acc[mi][ni], 0, 0, 0);
        asm volatile("s_waitcnt vmcnt(0)" ::: "memory");
        __syncthreads();
        cur ^= 1;
    }

    // epilogue: C/D layout col=lane&15, row=quad*4+reg
#pragma unroll
    for (int mi = 0; mi < 4; ++mi) {
        int row = m0 + wm + mi * 16 + quad * 4;
#pragma unroll
        for (int ni = 0; ni < 4; ++ni) {
            int col = n0 + wn + ni * 16 + lm;
            float bv = bias ? bias[col] : 0.f;
#pragma unroll
            for (int r = 0; r < 4; ++r) {
                int rr2 = row + r;
                if (rr2 < M && col < out_cols) {
                    float v = acc[mi][ni][r] + bv;
                    size_t off = (size_t)rr2 * ldc + col;
                    if (mode == 0)      Cb[off] = f2b(v);
                    else if (mode == 1) Cf[off] = v;
                    else                Cf[off] += v;
                }
            }
        }
    }
}

// ---------------------------------------------------------------------------
// prep kernels
// ---------------------------------------------------------------------------
__global__ void k_convert_x(const float* __restrict__ x, u16* __restrict__ hb,
                            u16* __restrict__ hNode) {
    int i = blockIdx.x * 256 + threadIdx.x;
    if (i >= N_NODES * DIM) return;
    int node = i / DIM, c = i - node * DIM;
    u16 v = f2b(x[i]);
    hb[((size_t)(c >> 3) * N_NODES + node) * 8 + (c & 7)] = v;
    hNode[i] = v;
}

// M = Wq @ Wk^T per (b,t):  M[e][d] = sum_j Wq[e][j] * Wk[d][j]
__global__ __launch_bounds__(256) void k_prep_M(
    const float* __restrict__ Wq, const float* __restrict__ Wk,
    float* __restrict__ Mf)
{
    __shared__ float aq[16][321];
    __shared__ float ak[16][321];
    int bt = blockIdx.z, e0 = blockIdx.y * 16, d0 = blockIdx.x * 16;
    const float* wq = Wq + ((size_t)bt * 320 + e0) * 320;
    const float* wk = Wk + ((size_t)bt * 320 + d0) * 320;
    for (int i = threadIdx.x; i < 16 * 320; i += 256) {
        int r = i / 320, j = i - r * 320;
        aq[r][j] = wq[(size_t)r * 320 + j];
        ak[r][j] = wk[(size_t)r * 320 + j];
    }
    __syncthreads();
    int te = threadIdx.x >> 4, td = threadIdx.x & 15;
    float s = 0.f;
    for (int j = 0; j < 320; ++j) s += aq[te][j] * ak[td][j];
    Mf[((size_t)bt * 320 + e0 + te) * 320 + d0 + td] = s;
}

// Bst_qkv cols 0-319 = M (bf16), 320-639 = Wv, >=673 zero. uint4 writes.
__global__ void k_prep_qkvW(const float* __restrict__ Mf, const float* __restrict__ Wv,
                            u16* __restrict__ Bst) {
    int i = blockIdx.x * 256 + threadIdx.x;
    if (i >= 27 * 40 * NPQ) return;
    int col = i % NPQ, kq = (i / NPQ) % 40, bt = i / (NPQ * 40);
    if (col >= 640 && col < QCOLS) return;  // ext cols written by k_prep_ext
    u16 tmp[8];
    if (col >= QCOLS) {
#pragma unroll
        for (int r = 0; r < 8; ++r) tmp[r] = 0;
    } else if (col < 320) {
#pragma unroll
        for (int r = 0; r < 8; ++r)
            tmp[r] = f2b(Mf[((size_t)bt * 320 + kq * 8 + r) * 320 + col]);
    } else {
#pragma unroll
        for (int r = 0; r < 8; ++r)
            tmp[r] = f2b(Wv[((size_t)bt * 320 + kq * 8 + r) * 320 + (col - 320)]);
    }
    *(uint4*)(&Bst[(((size_t)bt * 40 + kq) * NPQ + col) * 8]) = *(uint4*)tmp;
}

// ext columns: 640+c = (Wq@We^T) c<32 ; 672 = Wq@(be+bk) ; bias from bq
__global__ __launch_bounds__(256) void k_prep_ext(
    const float* __restrict__ Wq, const float* __restrict__ bq,
    const float* __restrict__ We, const float* __restrict__ be,
    const float* __restrict__ bk,
    u16* __restrict__ Bst, float* __restrict__ biasQkv)
{
    __shared__ float WeL[33 * 321];
    int bt = blockIdx.x, kt = blockIdx.y;  // kt 0..10
    for (int i = threadIdx.x; i < 33 * 320; i += 256) {
        int r = i / 320, d = i - r * 320;
        WeL[r * 321 + d] = (r < 32) ? We[((size_t)bt * 32 + r) * 320 + d]
                                    : (be[(size_t)bt * 320 + d] + bk[(size_t)bt * 320 + d]);
    }
    __syncthreads();
    if (kt < 10) {
        int k  = kt * 32 + (threadIdx.x >> 3);
        int ct = threadIdx.x & 7;
        const float* wq = Wq + ((size_t)bt * 320 + k) * 320;
        float dot[5] = {0.f, 0.f, 0.f, 0.f, 0.f};
        for (int d = 0; d < 320; ++d) {
            float w = wq[d];
            dot[0] += w * WeL[ct * 321 + d];
            dot[1] += w * WeL[(ct + 8) * 321 + d];
            dot[2] += w * WeL[(ct + 16) * 321 + d];
            dot[3] += w * WeL[(ct + 24) * 321 + d];
            dot[4] += w * WeL[32 * 321 + d];
        }
#pragma unroll
        for (int u = 0; u < 4; ++u)
            Bst[(((size_t)bt * 40 + (k >> 3)) * NPQ + 640 + ct + u * 8) * 8 + (k & 7)] = f2b(dot[u]);
        if (ct == 0)
            Bst[(((size_t)bt * 40 + (k >> 3)) * NPQ + 672) * 8 + (k & 7)] = f2b(dot[4]);
    } else {
        int c = threadIdx.x;
        if (c < 33) {
            const float* b = bq + (size_t)bt * 320;
            float s = 0.f;
            for (int d = 0; d < 320; ++d) s += b[d] * WeL[c * 321 + d];
            biasQkv[bt * 1024 + 640 + c] = s;
        }
    }
}

// bias cols 0-319 = Wk @ bq (per-row dot), 320-639 = bv, >=673 zero
__global__ __launch_bounds__(256) void k_prep_qkvB(
    const float* __restrict__ Wk, const float* __restrict__ bq,
    const float* __restrict__ bv, float* __restrict__ bias)
{
    int i = blockIdx.x * 256 + threadIdx.x;
    if (i >= 27 * NPQ) return;
    int col = i % NPQ, bt = i / NPQ;
    if (col < 320) {
        const float4* wr = (const float4*)(Wk + ((size_t)bt * 320 + col) * 320);
        const float4* bb = (const float4*)(bq + (size_t)bt * 320);
        float s = 0.f;
        for (int j = 0; j < 80; ++j) {
            float4 a = wr[j], b = bb[j];
            s += a.x * b.x + a.y * b.y + a.z * b.z + a.w * b.w;
        }
        bias[bt * 1024 + col] = s;
    } else if (col < 640) {
        bias[bt * 1024 + col] = bv[(size_t)bt * 320 + (col - 320)];
    } else if (col >= QCOLS) {
        bias[bt * 1024 + col] = 0.f;
    }
    // 640..672 from k_prep_ext
}

__global__ void k_prep_skipW(const float* __restrict__ Ws, u16* __restrict__ Bst) {
    int i = blockIdx.x * 256 + threadIdx.x;
    if (i >= 3 * 320 * 384) return;
    int col = i % 384, k = (i / 384) % 320, b = i / (384 * 320);
    float v = 0.f;
    if (col < 320)
        for (int t = 0; t < 9; ++t)
            v += Ws[((size_t)(b * 9 + t) * 320 + k) * 320 + col];
    Bst[(((size_t)b * 40 + (k >> 3)) * 384 + col) * 8 + (k & 7)] = f2b(v);
}
__global__ void k_prep_skipB(const float* __restrict__ bs, float* __restrict__ bias) {
    int i = blockIdx.x * 256 + threadIdx.x;
    if (i >= 3 * 384) return;
    int col = i % 384, b = i / 384;
    float v = 0.f;
    if (col < 320)
        for (int t = 0; t < 9; ++t) v += bs[(b * 9 + t) * 320 + col];
    bias[i] = v;
}

// We_all for batched s-GEMM: K rows k=t*34+j ; j<32 -> We[b*9+t][j], j==32 -> be,
// j==33 / k>=306 / col>=320 -> 0.  Layout [3][40][384][8].
__global__ void k_prep_sWe(const float* __restrict__ We, const float* __restrict__ be,
                           u16* __restrict__ Bst) {
    int i = blockIdx.x * 256 + threadIdx.x;
    if (i >= 3 * 40 * 384) return;
    int col = i % 384, kq = (i / 384) % 40, b = i / (384 * 40);
    u16 tmp[8];
#pragma unroll
    for (int r = 0; r < 8; ++r) {
        int k = kq * 8 + r;
        float v = 0.f;
        if (col < 320 && k < 306) {
            int t = k / 34, j = k - t * 34;
            int bt = b * 9 + t;
            if (j < 32)       v = We[((size_t)bt * 32 + j) * 320 + col];
            else if (j == 32) v = be[(size_t)bt * 320 + col];
        }
        tmp[r] = f2b(v);
    }
    *(uint4*)(&Bst[(((size_t)b * 40 + kq) * 384 + col) * 8]) = *(uint4*)tmp;
}

__global__ void k_prep_w1W(const float* __restrict__ W1, u16* __restrict__ Bst) {
    int i = blockIdx.x * 256 + threadIdx.x;
    if (i >= 320 * 128) return;
    int col = i & 127, k = i >> 7;
    float v = 0.f;
    if (col < 32)      v = W1[(size_t)k * 32 + col];
    else if (col < 64) v = W1[(size_t)(320 + k) * 32 + (col - 32)];
    Bst[((size_t)(k >> 3) * 128 + col) * 8 + (k & 7)] = f2b(v);
}

// ---------------------------------------------------------------------------
// CSR build
// ---------------------------------------------------------------------------
__global__ void k_csr_zero(int* __restrict__ cnt) {
    int i = blockIdx.x * 256 + threadIdx.x;
    if (i < NTYP * NPAD) cnt[i] = 0;
}
__global__ void k_csr_count(const int* __restrict__ eidx, int* __restrict__ cnt) {
    int i = blockIdx.x * 256 + threadIdx.x;
    if (i >= NTYP * N_EDGE) return;
    int t = i / N_EDGE, e = i - t * N_EDGE;
    int dst = eidx[(size_t)(t * 2 + 1) * N_EDGE + e];
    atomicAdd(&cnt[t * NPAD + dst], 1);
}
__global__ __launch_bounds__(1024) void k_csr_scan1(const int* __restrict__ cnt,
                                                    int* __restrict__ rowStart,
                                                    int* __restrict__ blockSum) {
    __shared__ int tmp[1024];
    int t = blockIdx.y, blk = blockIdx.x, tid = threadIdx.x;
    int idx = t * NPAD + blk * 1024 + tid;
    int v = cnt[idx];
    tmp[tid] = v;
    __syncthreads();
    for (int off = 1; off < 1024; off <<= 1) {
        int x = (tid >= off) ? tmp[tid - off] : 0;
        __syncthreads();
        tmp[tid] += x;
        __syncthreads();
    }
    rowStart[idx] = tmp[tid] - v;
    if (tid == 1023) blockSum[t * 64 + blk] = tmp[tid];
}
__global__ void k_csr_scan2(int* __restrict__ blockSum) {
    int t = threadIdx.x;
    if (t >= NTYP) return;
    int run = 0;
    for (int b = 0; b < BPT; ++b) {
        int v = blockSum[t * 64 + b];
        blockSum[t * 64 + b] = run;
        run += v;
    }
}
__global__ void k_csr_scan3(int* __restrict__ rowStart, const int* __restrict__ blockSum,
                            int* __restrict__ cursor) {
    int i = blockIdx.x * 256 + threadIdx.x;
    if (i >= NTYP * NPAD) return;
    int t = i / NPAD, n = i - t * NPAD;
    int v = rowStart[i] + blockSum[t * 64 + (n >> 10)];
    rowStart[i] = v;
    cursor[i] = v;
}
__global__ void k_csr_scatter(const int* __restrict__ eidx, int* __restrict__ cursor,
                              u16* __restrict__ sSrc, int* __restrict__ sEid) {
    int i = blockIdx.x * 256 + threadIdx.x;
    if (i >= NTYP * N_EDGE) return;
    int t = i / N_EDGE, e = i - t * N_EDGE;
    int src = eidx[(size_t)(t * 2) * N_EDGE + e];
    int dst = eidx[(size_t)(t * 2 + 1) * N_EDGE + e];
    int pos = atomicAdd(&cursor[t * NPAD + dst], 1);
    sSrc[(size_t)t * N_EDGE + pos] = (u16)src;
    sEid[(size_t)t * N_EDGE + pos] = e;
}

// ---------------------------------------------------------------------------
// Edge MLP for one type t
// ---------------------------------------------------------------------------
__global__ __launch_bounds__(256) void k_edge_mlp(
    const u16* __restrict__ Anodes, const int* __restrict__ eidx,
    const float* __restrict__ eattr, const float* __restrict__ W1,
    const float* __restrict__ b1, const float* __restrict__ W2,
    const float* __restrict__ b2, u16* __restrict__ outEa, int t)
{
    __shared__ float w1c[EDI][EH];
    __shared__ float w2s[EH][EH];
    __shared__ float b1s[EH], b2s[EH];
    int tid = threadIdx.x;
    for (int i = tid; i < EDI * EH; i += 256) w1c[i / EH][i % EH] = W1[(640 + i / EH) * EH + (i % EH)];
    for (int i = tid; i < EH * EH; i += 256) w2s[i / EH][i % EH] = W2[i];
    if (tid < EH) { b1s[tid] = b1[tid]; b2s[tid] = b2[tid]; }
    __syncthreads();

    int e = blockIdx.x * 256 + tid;
    if (e >= N_EDGE) return;
    int src = eidx[(size_t)(t * 2) * N_EDGE + e];
    int dst = eidx[(size_t)(t * 2 + 1) * N_EDGE + e];
    const float* eat = eattr + ((size_t)t * N_EDGE + e) * EDI;
    const u16* a1 = Anodes + (size_t)src * 64;
    const u16* a2 = Anodes + (size_t)dst * 64 + 32;

    float h1[EH];
#pragma unroll
    for (int j = 0; j < EH; ++j) h1[j] = b2f(a1[j]) + b2f(a2[j]) + b1s[j];
    for (int i = 0; i < EDI; ++i) {
        float v = eat[i];
#pragma unroll
        for (int j = 0; j < EH; ++j) h1[j] += v * w1c[i][j];
    }
#pragma unroll
    for (int j = 0; j < EH; ++j) h1[j] = h1[j] > 0.f ? h1[j] : 0.01f * h1[j];

    u16* orow = outEa + (size_t)e * EH;
    for (int j = 0; j < EH; ++j) {
        float o = b2s[j];
#pragma unroll
        for (int i = 0; i < EH; ++i) o += h1[i] * w2s[i][j];
        orow[j] = f2b(o);
    }
}

// ---------------------------------------------------------------------------
// Attention: one wave per dst node. Score uses the Wk-folded form:
//   alpha*sqrt(D) = q''[dst] . h[src]  +  qw . ea  +  qwbe
// where q'' = h(WqWk^T)+bqWk^T (qkv cols 0-319), qw = q We^T (640-671),
// qwbe = q.(be+bk) (672). h[src] read from node-major hNode (L2/L3-hot).
// v = (h Wv + bv)[src] (qkv cols 320-639). Lane l owns cols 4l..4l+3 + 256+l.
// ---------------------------------------------------------------------------
__global__ __launch_bounds__(256) void k_attn(
    const u16* __restrict__ qkv, const u16* __restrict__ hNode,
    const int* __restrict__ rowStart,
    const u16* __restrict__ sSrc, const int* __restrict__ sEid,
    const u16* __restrict__ ea, float* __restrict__ acc,
    u16* __restrict__ sST, int t34)
{
    int wave = threadIdx.x >> 6, lane = threadIdx.x & 63;
    int n = blockIdx.x * 4 + wave;
    if (n >= N_NODES) return;
    int eb = rowStart[n], ee = rowStart[n + 1];
    if (eb == ee) return;  // empty: acc untouched, s row stays zero

    const u16* qrow = qkv + (size_t)n * QLD;
    uint2 qv = *(const uint2*)(qrow + 4 * lane);
    float q40 = b2f_lo(qv.x), q41 = b2f_hi(qv.x);
    float q42 = b2f_lo(qv.y), q43 = b2f_hi(qv.y);
    float q1 = b2f(qrow[256 + lane]);
    float qwl = (lane < 33) ? b2f(qrow[640 + lane]) : 0.f;
    float qwbe = __shfl(qwl, 32, 64);
    float qw = (lane < 32) ? qwl : 0.f;
    const float RS = 0.05590169943749474f;  // 1/sqrt(320)

    float m = -INFINITY, l = 0.f, as = 0.f;
    float av0 = 0.f, av1 = 0.f, av2 = 0.f, av3 = 0.f, avt = 0.f;

    int ei = eb;
    for (; ei + 2 <= ee; ei += 2) {
        int s0 = sSrc[ei], s1 = sSrc[ei + 1];
        int id0 = sEid[ei], id1 = sEid[ei + 1];
        const u16* kr0 = hNode + (size_t)s0 * DIM;
        const u16* kr1 = hNode + (size_t)s1 * DIM;
        uint2 k0v = *(const uint2*)(kr0 + 4 * lane);
        uint2 k1v = *(const uint2*)(kr1 + 4 * lane);
        float k0t = b2f(kr0[256 + lane]);
        float k1t = b2f(kr1[256 + lane]);
        float ea0 = (lane < 32) ? b2f(ea[(size_t)id0 * 32 + lane]) : 0.f;
        float ea1 = (lane < 32) ? b2f(ea[(size_t)id1 * 32 + lane]) : 0.f;
        float d0 = qw * ea0 + q1 * k0t
                 + q40 * b2f_lo(k0v.x) + q41 * b2f_hi(k0v.x)
                 + q42 * b2f_lo(k0v.y) + q43 * b2f_hi(k0v.y);
        float d1 = qw * ea1 + q1 * k1t
                 + q40 * b2f_lo(k1v.x) + q41 * b2f_hi(k1v.x)
                 + q42 * b2f_lo(k1v.y) + q43 * b2f_hi(k1v.y);
#pragma unroll
        for (int off = 32; off > 0; off >>= 1) {
            d0 += __shfl_xor(d0, off, 64);
            d1 += __shfl_xor(d1, off, 64);
        }
        float a0 = (d0 + qwbe) * RS, a1 = (d1 + qwbe) * RS;
        float mn = fmaxf(m, fmaxf(a0, a1));
        float sc = __expf(m - mn);
        float p0 = __expf(a0 - mn), p1 = __expf(a1 - mn);
        l = l * sc + p0 + p1;
        const u16* vr0 = qkv + (size_t)s0 * QLD + 320;
        const u16* vr1 = qkv + (size_t)s1 * QLD + 320;
        uint2 v0v = *(const uint2*)(vr0 + 4 * lane);
        uint2 v1v = *(const uint2*)(vr1 + 4 * lane);
        float v0t = b2f(vr0[256 + lane]), v1t = b2f(vr1[256 + lane]);
        av0 = av0 * sc + p0 * b2f_lo(v0v.x) + p1 * b2f_lo(v1v.x);
        av1 = av1 * sc + p0 * b2f_hi(v0v.x) + p1 * b2f_hi(v1v.x);
        av2 = av2 * sc + p0 * b2f_lo(v0v.y) + p1 * b2f_lo(v1v.y);
        av3 = av3 * sc + p0 * b2f_hi(v0v.y) + p1 * b2f_hi(v1v.y);
        avt = avt * sc + p0 * v0t + p1 * v1t;
        as = as * sc + p0 * ea0 + p1 * ea1;
        m = mn;
    }
    if (ei < ee) {
        int s0 = sSrc[ei];
        int id0 = sEid[ei];
        const u16* kr0 = hNode + (size_t)s0 * DIM;
        uint2 k0v = *(const uint2*)(kr0 + 4 * lane);
        float k0t = b2f(kr0[256 + lane]);
        float ea0 = (lane < 32) ? b2f(ea[(size_t)id0 * 32 + lane]) : 0.f;
        float d0 = qw * ea0 + q1 * k0t
                 + q40 * b2f_lo(k0v.x) + q41 * b2f_hi(k0v.x)
                 + q42 * b2f_lo(k0v.y) + q43 * b2f_hi(k0v.y);
#pragma unroll
        for (int off = 32; off > 0; off >>= 1) d0 += __shfl_xor(d0, off, 64);
        float a0 = (d0 + qwbe) * RS;
        float mn = fmaxf(m, a0);
        float sc = __expf(m - mn), p0 = __expf(a0 - mn);
        l = l * sc + p0;
        const u16* vr0 = qkv + (size_t)s0 * QLD + 320;
        uint2 v0v = *(const uint2*)(vr0 + 4 * lane);
        float v0t = b2f(vr0[256 + lane]);
        av0 = av0 * sc + p0 * b2f_lo(v0v.x);
        av1 = av1 * sc + p0 * b2f_hi(v0v.x);
        av2 = av2 * sc + p0 * b2f_lo(v0v.y);
        av3 = av3 * sc + p0 * b2f_hi(v0v.y);
        avt = avt * sc + p0 * v0t;
        as = as * sc + p0 * ea0;
    }

    float inv = 1.f / l;
    float* arow = acc + (size_t)n * DIM;
    f32x4 pa = *(const f32x4*)(arow + 4 * lane);
    pa[0] += av0 * inv; pa[1] += av1 * inv;
    pa[2] += av2 * inv; pa[3] += av3 * inv;
    *(f32x4*)(arow + 4 * lane) = pa;
    arow[256 + lane] += avt * inv;
    if (lane < 33) {
        int k = t34 + lane;
        float sv = (lane < 32) ? as * inv : 1.f;  // flag multiplies be row
        sST[((size_t)(k >> 3) * N_NODES + n) * 8 + (k & 7)] = f2b(sv);
    }
}

// ---------------------------------------------------------------------------
// Post: x_ = lrelu(acc/9); graph layernorm; h = 0.5*(h + x_)
// maintains BOTH kq-major hbKq (GEMM A) and node-major hNode (attn k-gather)
// ---------------------------------------------------------------------------
__device__ __forceinline__ int lowerb(const int* a, int n, int v) {
    int lo = 0, hi = n;
    while (lo < hi) { int mid = (lo + hi) >> 1; if (a[mid] < v) lo = mid + 1; else hi = mid; }
    return lo;
}

__global__ __launch_bounds__(1024) void k_post(
    const float* __restrict__ acc, u16* __restrict__ hb, u16* __restrict__ hNode,
    const int* __restrict__ batch, const float* __restrict__ gamma,
    const float* __restrict__ beta)
{
    int g = blockIdx.x;
    int start = lowerb(batch, N_NODES, g);
    int end   = lowerb(batch, N_NODES, g + 1);
    int cnt = end - start;
    if (cnt == 0) return;
    int i0 = start * DIM, i1 = end * DIM;

    float s = 0.f, ss = 0.f;
    for (int i = i0 + threadIdx.x; i < i1; i += 1024) {
        float v = acc[i] * (1.f / 9.f);
        v = v > 0.f ? v : 0.01f * v;
        s += v; ss += v * v;
    }
    __shared__ float rs[16], rss[16];
#pragma unroll
    for (int off = 32; off > 0; off >>= 1) { s += __shfl_xor(s, off, 64); ss += __shfl_xor(ss, off, 64); }
    int wave = threadIdx.x >> 6, lane = threadIdx.x & 63;
    if (lane == 0) { rs[wave] = s; rss[wave] = ss; }
    __syncthreads();
    if (threadIdx.x == 0) {
        float S = 0.f, SS = 0.f;
        for (int w = 0; w < 16; ++w) { S += rs[w]; SS += rss[w]; }
        float norm = (float)cnt * DIM;
        float mean = S / norm;
        float var = SS / norm - mean * mean;
        rs[0] = mean;
        rss[0] = rsqrtf(var + 1e-5f);
    }
    __syncthreads();
    float mean = rs[0], rsig = rss[0];
    for (int i = i0 + threadIdx.x; i < i1; i += 1024) {
        float v = acc[i] * (1.f / 9.f);
        v = v > 0.f ? v : 0.01f * v;
        int node = i / DIM, c = i - node * DIM;
        float o = (v - mean) * rsig * gamma[c] + beta[c];
        u16 nb = f2b(0.5f * (b2f(hNode[i]) + o));
        hNode[i] = nb;
        hb[((size_t)(c >> 3) * N_NODES + node) * 8 + (c & 7)] = nb;
    }
}

__global__ __launch_bounds__(320) void k_maxpool(
    const u16* __restrict__ hb, const int* __restrict__ batch, float* __restrict__ out)
{
    int g = blockIdx.x, c = threadIdx.x;
    int start = lowerb(batch, N_NODES, g);
    int end   = lowerb(batch, N_NODES, g + 1);
    size_t base = (size_t)(c >> 3) * N_NODES * 8 + (c & 7);
    float m = -INFINITY;
    for (int n = start; n < end; ++n) m = fmaxf(m, b2f(hb[base + (size_t)n * 8]));
    out[(size_t)g * DIM + c] = m;
}

// ---------------------------------------------------------------------------
extern "C" void kernel_launch(void* const* d_in, const int* in_sizes, int n_in,
                              void* d_out, int out_size, void* d_ws, size_t ws_size,
                              hipStream_t stream)
{
    (void)in_sizes; (void)n_in; (void)out_size;
    const float* x     = (const float*)d_in[0];
    const int*   batch = (const int*)d_in[1];
    const int*   eidx  = (const int*)d_in[2];
    const float* eattr = (const float*)d_in[3];
    const float* W1 = (const float*)d_in[4];
    const float* b1 = (const float*)d_in[5];
    const float* W2 = (const float*)d_in[6];
    const float* b2 = (const float*)d_in[7];
    const float* Wq = (const float*)d_in[8];
    const float* bq = (const float*)d_in[9];
    const float* Wk = (const float*)d_in[10];
    const float* bk = (const float*)d_in[11];
    const float* Wv = (const float*)d_in[12];
    const float* bv = (const float*)d_in[13];
    const float* We = (const float*)d_in[14];
    const float* be = (const float*)d_in[15];
    const float* Ws = (const float*)d_in[16];
    const float* bs = (const float*)d_in[17];
    const float* gamma = (const float*)d_in[18];
    const float* beta  = (const float*)d_in[19];
    float* out = (float*)d_out;

    char* base = (char*)d_ws;
    size_t off = 0;
    auto carve = [&](size_t bytes) -> char* {
        char* r = base + off;
        off += (bytes + 255) & ~(size_t)255;
        return r;
    };
    u16*   hbKq    = (u16*)  carve((size_t)40 * N_NODES * 8 * 2 + 1024);  // 32 MB
    u16*   hNode   = (u16*)  carve((size_t)N_NODES * DIM * 2);            // 32 MB
    float* acc     = (float*)carve((size_t)N_NODES * DIM * 4);            // 64 MB
    u16*   qkv     = (u16*)  carve((size_t)N_NODES * QLD * 2);            // 67.6 MB
    u16*   sST     = (u16*)  carve((size_t)40 * N_NODES * 8 * 2 + 1024);  // 32 MB
    u16*   Anodes  = (u16*)  carve((size_t)N_NODES * 64 * 2);             // 6.4 MB
    float* Mf      = (float*)carve((size_t)27 * 320 * 320 * 4);           // 11 MB
    u16*   BstQkv  = (u16*)  carve((size_t)27 * 40 * NPQ * 8 * 2);        // 13.3 MB
    float* biasQkv = (float*)carve((size_t)27 * 1024 * 4);
    u16*   BstSkip = (u16*)  carve((size_t)3 * 40 * 384 * 8 * 2);
    float* biasSkip= (float*)carve((size_t)3 * 384 * 4);
    u16*   BstSWe  = (u16*)  carve((size_t)3 * 40 * 384 * 8 * 2);
    u16*   BstW1   = (u16*)  carve((size_t)40 * 128 * 8 * 2);
    int*   cnt     = (int*)  carve((size_t)NTYP * NPAD * 4);
    int*   rowStart= (int*)  carve((size_t)NTYP * NPAD * 4);
    int*   blockSum= (int*)  carve((size_t)NTYP * 64 * 4);
    u16*   sSrc    = (u16*)  carve((size_t)NTYP * N_EDGE * 2);
    int*   sEid    = (int*)  carve((size_t)NTYP * N_EDGE * 4);
    size_t fixed = off;
    size_t bigBytes   = (size_t)NTYP * N_EDGE * EH * 2;
    size_t smallBytes = (size_t)N_EDGE * EH * 2;
    int bigEa = (ws_size >= fixed + bigBytes + (1u << 20)) ? 1 : 0;
    u16* newEa = (u16*)carve(bigEa ? bigBytes : smallBytes);

    // prep
    k_convert_x<<<(N_NODES * DIM + 255) / 256, 256, 0, stream>>>(x, hbKq, hNode);
    k_prep_M<<<dim3(20, 20, 27), 256, 0, stream>>>(Wq, Wk, Mf);
    k_prep_qkvW<<<(27 * 40 * NPQ + 255) / 256, 256, 0, stream>>>(Mf, Wv, BstQkv);
    k_prep_ext<<<dim3(27, 11), 256, 0, stream>>>(Wq, bq, We, be, bk, BstQkv, biasQkv);
    k_prep_qkvB<<<(27 * NPQ + 255) / 256, 256, 0, stream>>>(Wk, bq, bv, biasQkv);
    k_prep_skipW<<<(3 * 320 * 384 + 255) / 256, 256, 0, stream>>>(Ws, BstSkip);
    k_prep_skipB<<<(3 * 384 + 255) / 256, 256, 0, stream>>>(bs, biasSkip);
    k_prep_sWe<<<(3 * 40 * 384 + 255) / 256, 256, 0, stream>>>(We, be, BstSWe);
    k_prep_w1W<<<(320 * 128 + 255) / 256, 256, 0, stream>>>(W1, BstW1);

    // CSR
    k_csr_zero<<<(NTYP * NPAD + 255) / 256, 256, 0, stream>>>(cnt);
    k_csr_count<<<(NTYP * N_EDGE + 255) / 256, 256, 0, stream>>>(eidx, cnt);
    k_csr_scan1<<<dim3(BPT, NTYP), 1024, 0, stream>>>(cnt, rowStart, blockSum);
    k_csr_scan2<<<1, 64, 0, stream>>>(blockSum);
    k_csr_scan3<<<(NTYP * NPAD + 255) / 256, 256, 0, stream>>>(rowStart, blockSum, cnt);
    k_csr_scatter<<<(NTYP * N_EDGE + 255) / 256, 256, 0, stream>>>(eidx, cnt, sSrc, sEid);

    const int mt = (N_NODES + 127) / 128;  // 391
    const int et = (N_EDGE + 255) / 256;
    // Anodes = x @ [W1a|W1b]
    gemm_kernel<<<dim3(1, mt), 256, 0, stream>>>(hbKq, N_NODES, BstW1, nullptr,
                                                 Anodes, nullptr, 64, 64, N_NODES, 128, 40, 0);
    if (bigEa) {
        for (int t = 0; t < NTYP; ++t)
            k_edge_mlp<<<dim3(et), 256, 0, stream>>>(
                Anodes, eidx, eattr, W1, b1, W2, b2, newEa + (size_t)t * N_EDGE * EH, t);
    }

    for (int b = 0; b < NBLK; ++b) {
        // acc = h @ sum_t(Ws) + sum_t(bs)
        gemm_kernel<<<dim3(3, mt), 256, 0, stream>>>(
            hbKq, N_NODES, BstSkip + (size_t)b * 40 * 384 * 8, biasSkip + b * 384,
            nullptr, acc, DIM, DIM, N_NODES, 384, 40, 1);
        hipMemsetAsync(sST, 0, (size_t)40 * N_NODES * 8 * 2, stream);
        for (int t = 0; t < NTYP; ++t) {
            int bt = b * NTYP + t;
            u16* eaT = bigEa ? (newEa + (size_t)t * N_EDGE * EH) : newEa;
            if (!bigEa)
                k_edge_mlp<<<dim3(et), 256, 0, stream>>>(
                    Anodes, eidx, eattr, W1, b1, W2, b2, eaT, t);
            gemm_kernel<<<dim3(6, mt), 256, 0, stream>>>(
                hbKq, N_NODES, BstQkv + (size_t)bt * 40 * NPQ * 8, biasQkv + bt * 1024,
                qkv, nullptr, QLD, QCOLS, N_NODES, NPQ, 40, 0);
            k_attn<<<dim3((N_NODES + 3) / 4), 256, 0, stream>>>(
                qkv, hNode, rowStart + t * NPAD, sSrc + (size_t)t * N_EDGE, sEid + (size_t)t * N_EDGE,
                eaT, acc, sST, t * 34);
        }
        // acc += s_all @ [We;be]_all   (batched over 9 types, K=306 padded 320)
        gemm_kernel<<<dim3(3, mt), 256, 0, stream>>>(
            sST, N_NODES, BstSWe + (size_t)b * 40 * 384 * 8, nullptr,
            nullptr, acc, DIM, DIM, N_NODES, 384, 40, 2);
        k_post<<<N_GRAPH, 1024, 0, stream>>>(acc, hbKq, hNode, batch,
                                             gamma + b * DIM, beta + b * DIM);
    }
    k_maxpool<<<N_GRAPH, 320, 0, stream>>>(hbKq, batch, out);
}

// Round 4
// 5522.967 us; speedup vs baseline: 1.1492x; 1.0443x over previous
//
#include <hip/hip_runtime.h>

#define N_NODES 50000
#define N_EDGE  150000
#define N_GRAPH 200
#define DIM     320
#define EDI     15
#define EH      32
#define NBLK    3
#define NTYP    9
#define NPAD    51200   // per-type CSR stride (50 blocks of 1024)
#define BPT     50      // scan blocks per type
#define QLD     360     // qkv' row stride (353 used cols), 16B-aligned rows
#define QCOLS   353     // q''(0-319) | qw(320-351) | qwbe(352)
#define NPQ     384     // qkv' GEMM N padded to 3 tiles of 128
// hAg layout (kq-major chunks of 8 k x N_NODES x 8 u16), 132 chunks total:
//   chunks 0-39   : h (DIM=320)
//   chunks 40-84  : slot 0 (type t, t&1==0): hv(320)|s(32)|flag|pad  (45 ch)
//   chunks 85-129 : slot 1 (t&1==1)
//   chunks 130-131: zero pad (memset once, never written)
// BstBig keeps the FULL 448-chunk K layout; 5 group GEMMs per block index
// into it: g0 K=132 (h+t0+t1, mode1), g1-g3 K=92 (B ch 130/220/310, mode2),
// g4 K=48 (B ch 400, mode2; tail hits zeroed B ch 445-447).
#define HAGCH   132
#define BIGCH   448

typedef unsigned short u16;
typedef unsigned int   u32;
typedef __bf16 bf16x8 __attribute__((ext_vector_type(8)));
typedef float  f32x4  __attribute__((ext_vector_type(4)));

__device__ __forceinline__ float b2f(u16 s) {
    u32 u = ((u32)s) << 16;
    return __builtin_bit_cast(float, u);
}
__device__ __forceinline__ float b2f_lo(u32 u) { return __builtin_bit_cast(float, u << 16); }
__device__ __forceinline__ float b2f_hi(u32 u) { return __builtin_bit_cast(float, u & 0xffff0000u); }
__device__ __forceinline__ u16 f2b(float f) {
    u32 u = __builtin_bit_cast(u32, f);
    u = (u + 0x7fffu + ((u >> 16) & 1u)) >> 16;
    return (u16)u;
}

// global -> LDS direct DMA, 16 B per lane. LDS dest = m0 + lane*16 (wave-uniform
// base), global src per-lane. Untracked by compiler => explicit vmcnt drains.
__device__ __forceinline__ void gll16(const u16* g, u32 ldsAddr) {
    u32 m0v = (u32)__builtin_amdgcn_readfirstlane((int)ldsAddr);
    asm volatile("s_mov_b32 m0, %0\n\t"
                 "global_load_lds_dwordx4 %1, off"
                 :: "s"(m0v), "v"((unsigned long long)(size_t)g)
                 : "memory");
}

// ---------------------------------------------------------------------------
// bf16 MFMA GEMM — LDS-staged double-buffered, T1 XCD-aware bijective swizzle,
// optional z-batching (per-z A/B/C strides in elements). Inputs kq-major:
// element (k, m) at ((k>>3)*Stride + m)*8 + (k&7). Tile 128x128, BK=32,
// 4 waves of 64x64. mode 0: Cb=bf16 ; 1: Cf=f32 (+bias) ; 2: Cf += f32
// ---------------------------------------------------------------------------
__global__ __launch_bounds__(256) void gemm_kernel(
    const u16* __restrict__ A, int Mstride,
    const u16* __restrict__ Bst, const float* __restrict__ bias,
    u16* __restrict__ Cb, float* __restrict__ Cf,
    int ldc, int out_cols, int M, int NP, int KQ, int mode,
    int zA, int zB, int zC)
{
    A += (size_t)blockIdx.z * zA;
    Bst += (size_t)blockIdx.z * zB;
    if (Cb) Cb += (size_t)blockIdx.z * zC;
    if (Cf) Cf += (size_t)blockIdx.z * zC;

    const int tid = threadIdx.x;
    const int wave = tid >> 6, lane = tid & 63;

    // XCD swizzle (bijective): XCD x gets a contiguous logical range
    const int nwg = gridDim.x * gridDim.y;
    const int flat = blockIdx.y * gridDim.x + blockIdx.x;
    const int qq = nwg >> 3, rr = nwg & 7;
    const int xcd = flat & 7, loc = flat >> 3;
    const int swz = (xcd < rr ? xcd * (qq + 1) : rr * (qq + 1) + (xcd - rr) * qq) + loc;
    const int n0 = (swz % gridDim.x) * 128, m0 = (swz / gridDim.x) * 128;

    const int wm = (wave & 1) << 6, wn = (wave >> 1) << 6;
    const int lm = lane & 15, quad = lane >> 4;

    // [buf][A/B][chunk(4)][node(128)] of 16B slots
    __shared__ uint4 smem[2][2][512];
    const u32 ldsBase = (u32)(size_t)&smem[0][0][0];

    f32x4 acc[4][4] = {};
    const int nIter = KQ >> 2;   // K-steps of 32 (4 chunks of 8)

    auto stage = [&](int s, int buf) {
        const int c0 = s << 2;
        const u32 bufBase = ldsBase + (u32)buf * 16384u;
#pragma unroll
        for (int u = 0; u < 2; ++u) {
            const int i = wave + (u << 2);
            const int chunk = i >> 1, half = (i & 1) << 6;
            const u16* ga = A + ((size_t)(c0 + chunk) * Mstride + m0 + half + lane) * 8;
            gll16(ga, bufBase + (u32)i * 1024u);
            const u16* gb = Bst + ((size_t)(c0 + chunk) * NP + n0 + half + lane) * 8;
            gll16(gb, bufBase + 8192u + (u32)i * 1024u);
        }
    };

    stage(0, 0);
    asm volatile("s_waitcnt vmcnt(0)" ::: "memory");
    __syncthreads();

    int cur = 0;
    for (int s = 0; s < nIter; ++s) {
        if (s + 1 < nIter) stage(s + 1, cur ^ 1);   // prefetch next tile
        const uint4* aT = &smem[cur][0][0];
        const uint4* bT = &smem[cur][1][0];
        bf16x8 af[4], bfr[4];
#pragma unroll
        for (int mi = 0; mi < 4; ++mi)
            af[mi] = __builtin_bit_cast(bf16x8, aT[quad * 128 + wm + mi * 16 + lm]);
#pragma unroll
        for (int ni = 0; ni < 4; ++ni)
            bfr[ni] = __builtin_bit_cast(bf16x8, bT[quad * 128 + wn + ni * 16 + lm]);
#pragma unroll
        for (int mi = 0; mi < 4; ++mi)
#pragma unroll
            for (int ni = 0; ni < 4; ++ni)
                acc[mi][ni] = __builtin_amdgcn_mfma_f32_16x16x32_bf16(af[mi], bfr[ni], acc[mi][ni], 0, 0, 0);
        asm volatile("s_waitcnt vmcnt(0)" ::: "memory");
        __syncthreads();
        cur ^= 1;
    }

    // epilogue: C/D layout col=lane&15, row=quad*4+reg
#pragma unroll
    for (int mi = 0; mi < 4; ++mi) {
        int row = m0 + wm + mi * 16 + quad * 4;
#pragma unroll
        for (int ni = 0; ni < 4; ++ni) {
            int col = n0 + wn + ni * 16 + lm;
            float bv = bias ? bias[col] : 0.f;
#pragma unroll
            for (int r = 0; r < 4; ++r) {
                int rr2 = row + r;
                if (rr2 < M && col < out_cols) {
                    float v = acc[mi][ni][r] + bv;
                    size_t off = (size_t)rr2 * ldc + col;
                    if (mode == 0)      Cb[off] = f2b(v);
                    else if (mode == 1) Cf[off] = v;
                    else                Cf[off] += v;
                }
            }
        }
    }
}

// ---------------------------------------------------------------------------
// prep kernels
// ---------------------------------------------------------------------------
__global__ void k_convert_x(const float* __restrict__ x, u16* __restrict__ hb,
                            u16* __restrict__ hNode) {
    int i = blockIdx.x * 256 + threadIdx.x;
    if (i >= N_NODES * DIM) return;
    int node = i / DIM, c = i - node * DIM;
    u16 v = f2b(x[i]);
    hb[((size_t)(c >> 3) * N_NODES + node) * 8 + (c & 7)] = v;
    hNode[i] = v;
}

// W [27][320][320] f32 -> kq-major bf16 over contraction j:
// T[((bt*40 + (j>>3))*320 + e)*8 + (j&7)] = W[(bt*320+e)*320 + j]
__global__ void k_prep_wT(const float* __restrict__ W, u16* __restrict__ T) {
    int i = blockIdx.x * 256 + threadIdx.x;
    if (i >= 27 * 40 * 320) return;
    int e = i % 320, jq = (i / 320) % 40, bt = i / (320 * 40);
    const float* src = W + ((size_t)bt * 320 + e) * 320 + jq * 8;
    u16 tmp[8];
#pragma unroll
    for (int r = 0; r < 8; ++r) tmp[r] = f2b(src[r]);
    *(uint4*)(&T[(((size_t)bt * 40 + jq) * 320 + e) * 8]) = *(uint4*)tmp;
}

// Bst_qkv cols 0-319 = M=WqWk^T (bf16, from Mb), >=353 zero. uint4 writes.
__global__ void k_prep_qkvW(const u16* __restrict__ Mb, u16* __restrict__ Bst) {
    int i = blockIdx.x * 256 + threadIdx.x;
    if (i >= 27 * 40 * NPQ) return;
    int col = i % NPQ, kq = (i / NPQ) % 40, bt = i / (NPQ * 40);
    if (col >= 320 && col < QCOLS) return;  // ext cols written by k_prep_ext
    u16 tmp[8];
    if (col >= QCOLS) {
#pragma unroll
        for (int r = 0; r < 8; ++r) tmp[r] = 0;
    } else {
#pragma unroll
        for (int r = 0; r < 8; ++r)
            tmp[r] = Mb[((size_t)bt * 320 + kq * 8 + r) * 320 + col];
    }
    *(uint4*)(&Bst[(((size_t)bt * 40 + kq) * NPQ + col) * 8]) = *(uint4*)tmp;
}

// ext columns: 320+c = (Wq@We^T) c<32 ; 352 = Wq@(be+bk) ; bias from bq
__global__ __launch_bounds__(256) void k_prep_ext(
    const float* __restrict__ Wq, const float* __restrict__ bq,
    const float* __restrict__ We, const float* __restrict__ be,
    const float* __restrict__ bk,
    u16* __restrict__ Bst, float* __restrict__ biasQkv)
{
    __shared__ float WeL[33 * 321];
    int bt = blockIdx.x, kt = blockIdx.y;  // kt 0..10
    for (int i = threadIdx.x; i < 33 * 320; i += 256) {
        int r = i / 320, d = i - r * 320;
        WeL[r * 321 + d] = (r < 32) ? We[((size_t)bt * 32 + r) * 320 + d]
                                    : (be[(size_t)bt * 320 + d] + bk[(size_t)bt * 320 + d]);
    }
    __syncthreads();
    if (kt < 10) {
        int k  = kt * 32 + (threadIdx.x >> 3);
        int ct = threadIdx.x & 7;
        const float* wq = Wq + ((size_t)bt * 320 + k) * 320;
        float dot[5] = {0.f, 0.f, 0.f, 0.f, 0.f};
        for (int d = 0; d < 320; ++d) {
            float w = wq[d];
            dot[0] += w * WeL[ct * 321 + d];
            dot[1] += w * WeL[(ct + 8) * 321 + d];
            dot[2] += w * WeL[(ct + 16) * 321 + d];
            dot[3] += w * WeL[(ct + 24) * 321 + d];
            dot[4] += w * WeL[32 * 321 + d];
        }
#pragma unroll
        for (int u = 0; u < 4; ++u)
            Bst[(((size_t)bt * 40 + (k >> 3)) * NPQ + 320 + ct + u * 8) * 8 + (k & 7)] = f2b(dot[u]);
        if (ct == 0)
            Bst[(((size_t)bt * 40 + (k >> 3)) * NPQ + 352) * 8 + (k & 7)] = f2b(dot[4]);
    } else {
        int c = threadIdx.x;
        if (c < 33) {
            const float* b = bq + (size_t)bt * 320;
            float s = 0.f;
            for (int d = 0; d < 320; ++d) s += b[d] * WeL[c * 321 + d];
            biasQkv[bt * NPQ + 320 + c] = s;
        }
    }
}

// bias cols 0-319 = Wk @ bq (per-row dot), 353-383 zero (320-352 from ext)
__global__ __launch_bounds__(256) void k_prep_qkvB(
    const float* __restrict__ Wk, const float* __restrict__ bq,
    float* __restrict__ bias)
{
    int i = blockIdx.x * 256 + threadIdx.x;
    if (i >= 27 * NPQ) return;
    int col = i % NPQ, bt = i / NPQ;
    if (col < 320) {
        const float4* wr = (const float4*)(Wk + ((size_t)bt * 320 + col) * 320);
        const float4* bb = (const float4*)(bq + (size_t)bt * 320);
        float s = 0.f;
        for (int j = 0; j < 80; ++j) {
            float4 a = wr[j], b = bb[j];
            s += a.x * b.x + a.y * b.y + a.z * b.z + a.w * b.w;
        }
        bias[bt * NPQ + col] = s;
    } else if (col >= QCOLS) {
        bias[bt * NPQ + col] = 0.f;
    }
}

__global__ void k_prep_skipB(const float* __restrict__ bs, float* __restrict__ bias) {
    int i = blockIdx.x * 256 + threadIdx.x;
    if (i >= 3 * 384) return;
    int col = i % 384, b = i / 384;
    float v = 0.f;
    if (col < 320)
        for (int t = 0; t < 9; ++t) v += bs[(b * 9 + t) * 320 + col];
    bias[i] = v;
}

// Big-GEMM B: [3][448 chunks][384][8]. k<320: sum_t Ws ; else per type t
// (360 k each): kl<320 -> Wv[b,t][kl], kl<352 -> We[b,t][kl-320],
// kl==352 -> be+bv (flag row), else 0. col>=320 -> 0. Chunks 445-447 zero.
__global__ void k_prep_bigB(const float* __restrict__ Ws, const float* __restrict__ Wv,
                            const float* __restrict__ We, const float* __restrict__ be,
                            const float* __restrict__ bv, u16* __restrict__ Bst) {
    int i = blockIdx.x * 256 + threadIdx.x;
    if (i >= 3 * BIGCH * 384) return;
    int col = i % 384, q = (i / 384) % BIGCH, b = i / (384 * BIGCH);
    u16 tmp[8];
#pragma unroll
    for (int r = 0; r < 8; ++r) {
        int k = q * 8 + r;
        float v = 0.f;
        if (col < 320) {
            if (k < 320) {
                for (int t = 0; t < 9; ++t)
                    v += Ws[((size_t)(b * 9 + t) * 320 + k) * 320 + col];
            } else {
                int kk = k - 320, t = kk / 360, kl = kk - t * 360;
                if (t < 9) {
                    int bt = b * 9 + t;
                    if (kl < 320)       v = Wv[((size_t)bt * 320 + kl) * 320 + col];
                    else if (kl < 352)  v = We[((size_t)bt * 32 + (kl - 320)) * 320 + col];
                    else if (kl == 352) v = be[(size_t)bt * 320 + col] + bv[(size_t)bt * 320 + col];
                }
            }
        }
        tmp[r] = f2b(v);
    }
    *(uint4*)(&Bst[(((size_t)b * BIGCH + q) * 384 + col) * 8]) = *(uint4*)tmp;
}

__global__ void k_prep_w1W(const float* __restrict__ W1, u16* __restrict__ Bst) {
    int i = blockIdx.x * 256 + threadIdx.x;
    if (i >= 320 * 128) return;
    int col = i & 127, k = i >> 7;
    float v = 0.f;
    if (col < 32)      v = W1[(size_t)k * 32 + col];
    else if (col < 64) v = W1[(size_t)(320 + k) * 32 + (col - 32)];
    Bst[((size_t)(k >> 3) * 128 + col) * 8 + (k & 7)] = f2b(v);
}

// ---------------------------------------------------------------------------
// CSR build
// ---------------------------------------------------------------------------
__global__ void k_csr_zero(int* __restrict__ cnt) {
    int i = blockIdx.x * 256 + threadIdx.x;
    if (i < NTYP * NPAD) cnt[i] = 0;
}
__global__ void k_csr_count(const int* __restrict__ eidx, int* __restrict__ cnt) {
    int i = blockIdx.x * 256 + threadIdx.x;
    if (i >= NTYP * N_EDGE) return;
    int t = i / N_EDGE, e = i - t * N_EDGE;
    int dst = eidx[(size_t)(t * 2 + 1) * N_EDGE + e];
    atomicAdd(&cnt[t * NPAD + dst], 1);
}
__global__ __launch_bounds__(1024) void k_csr_scan1(const int* __restrict__ cnt,
                                                    int* __restrict__ rowStart,
                                                    int* __restrict__ blockSum) {
    __shared__ int tmp[1024];
    int t = blockIdx.y, blk = blockIdx.x, tid = threadIdx.x;
    int idx = t * NPAD + blk * 1024 + tid;
    int v = cnt[idx];
    tmp[tid] = v;
    __syncthreads();
    for (int off = 1; off < 1024; off <<= 1) {
        int x = (tid >= off) ? tmp[tid - off] : 0;
        __syncthreads();
        tmp[tid] += x;
        __syncthreads();
    }
    rowStart[idx] = tmp[tid] - v;
    if (tid == 1023) blockSum[t * 64 + blk] = tmp[tid];
}
__global__ void k_csr_scan2(int* __restrict__ blockSum) {
    int t = threadIdx.x;
    if (t >= NTYP) return;
    int run = 0;
    for (int b = 0; b < BPT; ++b) {
        int v = blockSum[t * 64 + b];
        blockSum[t * 64 + b] = run;
        run += v;
    }
}
__global__ void k_csr_scan3(int* __restrict__ rowStart, const int* __restrict__ blockSum,
                            int* __restrict__ cursor) {
    int i = blockIdx.x * 256 + threadIdx.x;
    if (i >= NTYP * NPAD) return;
    int t = i / NPAD, n = i - t * NPAD;
    int v = rowStart[i] + blockSum[t * 64 + (n >> 10)];
    rowStart[i] = v;
    cursor[i] = v;
}
__global__ void k_csr_scatter(const int* __restrict__ eidx, int* __restrict__ cursor,
                              u16* __restrict__ sSrc, int* __restrict__ sEid) {
    int i = blockIdx.x * 256 + threadIdx.x;
    if (i >= NTYP * N_EDGE) return;
    int t = i / N_EDGE, e = i - t * N_EDGE;
    int src = eidx[(size_t)(t * 2) * N_EDGE + e];
    int dst = eidx[(size_t)(t * 2 + 1) * N_EDGE + e];
    int pos = atomicAdd(&cursor[t * NPAD + dst], 1);
    sSrc[(size_t)t * N_EDGE + pos] = (u16)src;
    sEid[(size_t)t * N_EDGE + pos] = e;
}

// ---------------------------------------------------------------------------
// Edge MLP for one type t
// ---------------------------------------------------------------------------
__global__ __launch_bounds__(256) void k_edge_mlp(
    const u16* __restrict__ Anodes, const int* __restrict__ eidx,
    const float* __restrict__ eattr, const float* __restrict__ W1,
    const float* __restrict__ b1, const float* __restrict__ W2,
    const float* __restrict__ b2, u16* __restrict__ outEa, int t)
{
    __shared__ float w1c[EDI][EH];
    __shared__ float w2s[EH][EH];
    __shared__ float b1s[EH], b2s[EH];
    int tid = threadIdx.x;
    for (int i = tid; i < EDI * EH; i += 256) w1c[i / EH][i % EH] = W1[(640 + i / EH) * EH + (i % EH)];
    for (int i = tid; i < EH * EH; i += 256) w2s[i / EH][i % EH] = W2[i];
    if (tid < EH) { b1s[tid] = b1[tid]; b2s[tid] = b2[tid]; }
    __syncthreads();

    int e = blockIdx.x * 256 + tid;
    if (e >= N_EDGE) return;
    int src = eidx[(size_t)(t * 2) * N_EDGE + e];
    int dst = eidx[(size_t)(t * 2 + 1) * N_EDGE + e];
    const float* eat = eattr + ((size_t)t * N_EDGE + e) * EDI;
    const u16* a1 = Anodes + (size_t)src * 64;
    const u16* a2 = Anodes + (size_t)dst * 64 + 32;

    float h1[EH];
#pragma unroll
    for (int j = 0; j < EH; ++j) h1[j] = b2f(a1[j]) + b2f(a2[j]) + b1s[j];
    for (int i = 0; i < EDI; ++i) {
        float v = eat[i];
#pragma unroll
        for (int j = 0; j < EH; ++j) h1[j] += v * w1c[i][j];
    }
#pragma unroll
    for (int j = 0; j < EH; ++j) h1[j] = h1[j] > 0.f ? h1[j] : 0.01f * h1[j];

    u16* orow = outEa + (size_t)e * EH;
    for (int j = 0; j < EH; ++j) {
        float o = b2s[j];
#pragma unroll
        for (int i = 0; i < EH; ++i) o += h1[i] * w2s[i][j];
        orow[j] = f2b(o);
    }
}

// ---------------------------------------------------------------------------
// Attention, v-folded: score = (q''[dst].h[src] + qw.ea + qwbe)/sqrt(D).
// Aggregates hv = sum p*h[src]/l IN h-SPACE (reusing the loaded h values);
// Wv applied later by the group GEMMs (sum w = 1 => v-proj commutes).
// Writes hv(320)+s(32)+flag into hAg chunks [cb .. cb+44], cb = 40+(t&1)*45.
// Empty nodes write zero rows (flag 0 gates be+bv).
// ---------------------------------------------------------------------------
__global__ __launch_bounds__(256) void k_attn(
    const u16* __restrict__ qkv, const u16* __restrict__ hNode,
    const int* __restrict__ rowStart,
    const u16* __restrict__ sSrc, const int* __restrict__ sEid,
    const u16* __restrict__ ea, u16* __restrict__ hA, int cb)
{
    int wave = threadIdx.x >> 6, lane = threadIdx.x & 63;
    int n = blockIdx.x * 4 + wave;
    if (n >= N_NODES) return;
    int eb = rowStart[n], ee = rowStart[n + 1];

    float l = 0.f, as = 0.f;
    float av0 = 0.f, av1 = 0.f, av2 = 0.f, av3 = 0.f, avt = 0.f;

    if (eb != ee) {
        const u16* qrow = qkv + (size_t)n * QLD;
        uint2 qv = *(const uint2*)(qrow + 4 * lane);
        float q40 = b2f_lo(qv.x), q41 = b2f_hi(qv.x);
        float q42 = b2f_lo(qv.y), q43 = b2f_hi(qv.y);
        float q1 = b2f(qrow[256 + lane]);
        float qwl = (lane < 33) ? b2f(qrow[320 + lane]) : 0.f;
        float qwbe = __shfl(qwl, 32, 64);
        float qw = (lane < 32) ? qwl : 0.f;
        const float RS = 0.05590169943749474f;  // 1/sqrt(320)
        float m = -INFINITY;

        int ei = eb;
        for (; ei + 2 <= ee; ei += 2) {
            int s0 = sSrc[ei], s1 = sSrc[ei + 1];
            int id0 = sEid[ei], id1 = sEid[ei + 1];
            const u16* kr0 = hNode + (size_t)s0 * DIM;
            const u16* kr1 = hNode + (size_t)s1 * DIM;
            uint2 k0v = *(const uint2*)(kr0 + 4 * lane);
            uint2 k1v = *(const uint2*)(kr1 + 4 * lane);
            float k00 = b2f_lo(k0v.x), k01 = b2f_hi(k0v.x);
            float k02 = b2f_lo(k0v.y), k03 = b2f_hi(k0v.y);
            float k10 = b2f_lo(k1v.x), k11 = b2f_hi(k1v.x);
            float k12 = b2f_lo(k1v.y), k13 = b2f_hi(k1v.y);
            float k0t = b2f(kr0[256 + lane]);
            float k1t = b2f(kr1[256 + lane]);
            float ea0 = (lane < 32) ? b2f(ea[(size_t)id0 * 32 + lane]) : 0.f;
            float ea1 = (lane < 32) ? b2f(ea[(size_t)id1 * 32 + lane]) : 0.f;
            float d0 = qw * ea0 + q1 * k0t + q40 * k00 + q41 * k01 + q42 * k02 + q43 * k03;
            float d1 = qw * ea1 + q1 * k1t + q40 * k10 + q41 * k11 + q42 * k12 + q43 * k13;
#pragma unroll
            for (int off = 32; off > 0; off >>= 1) {
                d0 += __shfl_xor(d0, off, 64);
                d1 += __shfl_xor(d1, off, 64);
            }
            float a0 = (d0 + qwbe) * RS, a1 = (d1 + qwbe) * RS;
            float mn = fmaxf(m, fmaxf(a0, a1));
            float sc = __expf(m - mn);
            float p0 = __expf(a0 - mn), p1 = __expf(a1 - mn);
            l = l * sc + p0 + p1;
            av0 = av0 * sc + p0 * k00 + p1 * k10;
            av1 = av1 * sc + p0 * k01 + p1 * k11;
            av2 = av2 * sc + p0 * k02 + p1 * k12;
            av3 = av3 * sc + p0 * k03 + p1 * k13;
            avt = avt * sc + p0 * k0t + p1 * k1t;
            as = as * sc + p0 * ea0 + p1 * ea1;
            m = mn;
        }
        if (ei < ee) {
            int s0 = sSrc[ei];
            int id0 = sEid[ei];
            const u16* kr0 = hNode + (size_t)s0 * DIM;
            uint2 k0v = *(const uint2*)(kr0 + 4 * lane);
            float k00 = b2f_lo(k0v.x), k01 = b2f_hi(k0v.x);
            float k02 = b2f_lo(k0v.y), k03 = b2f_hi(k0v.y);
            float k0t = b2f(kr0[256 + lane]);
            float ea0 = (lane < 32) ? b2f(ea[(size_t)id0 * 32 + lane]) : 0.f;
            float d0 = qw * ea0 + q1 * k0t + q40 * k00 + q41 * k01 + q42 * k02 + q43 * k03;
#pragma unroll
            for (int off = 32; off > 0; off >>= 1) d0 += __shfl_xor(d0, off, 64);
            float a0 = (d0 + qwbe) * RS;
            float mn = fmaxf(m, a0);
            float sc = __expf(m - mn), p0 = __expf(a0 - mn);
            l = l * sc + p0;
            av0 = av0 * sc + p0 * k00;
            av1 = av1 * sc + p0 * k01;
            av2 = av2 * sc + p0 * k02;
            av3 = av3 * sc + p0 * k03;
            avt = avt * sc + p0 * k0t;
            as = as * sc + p0 * ea0;
        }
    }

    float inv = (l > 0.f) ? 1.f / l : 0.f;
    // hv cols 4l..4l+3 -> chunk cb+(l>>1), offset (l&1)*4 (8B store)
    u32 w0 = (u32)f2b(av0 * inv) | ((u32)f2b(av1 * inv) << 16);
    u32 w1 = (u32)f2b(av2 * inv) | ((u32)f2b(av3 * inv) << 16);
    uint2 wv; wv.x = w0; wv.y = w1;
    *(uint2*)(hA + ((size_t)(cb + (lane >> 1)) * N_NODES + n) * 8 + (lane & 1) * 4) = wv;
    // hv col 256+l
    hA[((size_t)(cb + 32 + (lane >> 3)) * N_NODES + n) * 8 + (lane & 7)] = f2b(avt * inv);
    if (lane < 32) {
        hA[((size_t)(cb + 40 + (lane >> 3)) * N_NODES + n) * 8 + (lane & 7)] = f2b(as * inv);
    } else if (lane == 32) {
        uint4 fz; fz.x = (eb != ee) ? 0x3f80u : 0u; fz.y = 0u; fz.z = 0u; fz.w = 0u;
        *(uint4*)(hA + ((size_t)(cb + 44) * N_NODES + n) * 8) = fz;  // flag + zero pad
    }
}

// ---------------------------------------------------------------------------
// Post: x_ = lrelu(acc/9); graph layernorm; h = 0.5*(h + x_)
// maintains BOTH kq-major hAg[0:40] (GEMM A) and node-major hNode (attn gather)
// ---------------------------------------------------------------------------
__device__ __forceinline__ int lowerb(const int* a, int n, int v) {
    int lo = 0, hi = n;
    while (lo < hi) { int mid = (lo + hi) >> 1; if (a[mid] < v) lo = mid + 1; else hi = mid; }
    return lo;
}

__global__ __launch_bounds__(1024) void k_post(
    const float* __restrict__ acc, u16* __restrict__ hb, u16* __restrict__ hNode,
    const int* __restrict__ batch, const float* __restrict__ gamma,
    const float* __restrict__ beta)
{
    int g = blockIdx.x;
    int start = lowerb(batch, N_NODES, g);
    int end   = lowerb(batch, N_NODES, g + 1);
    int cnt = end - start;
    if (cnt == 0) return;
    int i0 = start * DIM, i1 = end * DIM;

    float s = 0.f, ss = 0.f;
    for (int i = i0 + threadIdx.x; i < i1; i += 1024) {
        float v = acc[i] * (1.f / 9.f);
        v = v > 0.f ? v : 0.01f * v;
        s += v; ss += v * v;
    }
    __shared__ float rs[16], rss[16];
#pragma unroll
    for (int off = 32; off > 0; off >>= 1) { s += __shfl_xor(s, off, 64); ss += __shfl_xor(ss, off, 64); }
    int wave = threadIdx.x >> 6, lane = threadIdx.x & 63;
    if (lane == 0) { rs[wave] = s; rss[wave] = ss; }
    __syncthreads();
    if (threadIdx.x == 0) {
        float S = 0.f, SS = 0.f;
        for (int w = 0; w < 16; ++w) { S += rs[w]; SS += rss[w]; }
        float norm = (float)cnt * DIM;
        float mean = S / norm;
        float var = SS / norm - mean * mean;
        rs[0] = mean;
        rss[0] = rsqrtf(var + 1e-5f);
    }
    __syncthreads();
    float mean = rs[0], rsig = rss[0];
    for (int i = i0 + threadIdx.x; i < i1; i += 1024) {
        float v = acc[i] * (1.f / 9.f);
        v = v > 0.f ? v : 0.01f * v;
        int node = i / DIM, c = i - node * DIM;
        float o = (v - mean) * rsig * gamma[c] + beta[c];
        u16 nb = f2b(0.5f * (b2f(hNode[i]) + o));
        hNode[i] = nb;
        hb[((size_t)(c >> 3) * N_NODES + node) * 8 + (c & 7)] = nb;
    }
}

__global__ __launch_bounds__(320) void k_maxpool(
    const u16* __restrict__ hb, const int* __restrict__ batch, float* __restrict__ out)
{
    int g = blockIdx.x, c = threadIdx.x;
    int start = lowerb(batch, N_NODES, g);
    int end   = lowerb(batch, N_NODES, g + 1);
    size_t base = (size_t)(c >> 3) * N_NODES * 8 + (c & 7);
    float m = -INFINITY;
    for (int n = start; n < end; ++n) m = fmaxf(m, b2f(hb[base + (size_t)n * 8]));
    out[(size_t)g * DIM + c] = m;
}

// ---------------------------------------------------------------------------
extern "C" void kernel_launch(void* const* d_in, const int* in_sizes, int n_in,
                              void* d_out, int out_size, void* d_ws, size_t ws_size,
                              hipStream_t stream)
{
    (void)in_sizes; (void)n_in; (void)out_size;
    const float* x     = (const float*)d_in[0];
    const int*   batch = (const int*)d_in[1];
    const int*   eidx  = (const int*)d_in[2];
    const float* eattr = (const float*)d_in[3];
    const float* W1 = (const float*)d_in[4];
    const float* b1 = (const float*)d_in[5];
    const float* W2 = (const float*)d_in[6];
    const float* b2 = (const float*)d_in[7];
    const float* Wq = (const float*)d_in[8];
    const float* bq = (const float*)d_in[9];
    const float* Wk = (const float*)d_in[10];
    const float* bk = (const float*)d_in[11];
    const float* Wv = (const float*)d_in[12];
    const float* bv = (const float*)d_in[13];
    const float* We = (const float*)d_in[14];
    const float* be = (const float*)d_in[15];
    const float* Ws = (const float*)d_in[16];
    const float* bs = (const float*)d_in[17];
    const float* gamma = (const float*)d_in[18];
    const float* beta  = (const float*)d_in[19];
    float* out = (float*)d_out;

    char* base = (char*)d_ws;
    size_t off = 0;
    auto carve = [&](size_t bytes) -> char* {
        char* r = base + off;
        off += (bytes + 255) & ~(size_t)255;
        return r;
    };
    // fixed footprint ~270.6 MB (< Round-2-proven 271.6 MB)
    u16*   hAg     = (u16*)  carve((size_t)HAGCH * N_NODES * 8 * 2 + 1024); // 105.6 MB
    u16*   hNode   = (u16*)  carve((size_t)N_NODES * DIM * 2);              // 32 MB
    float* acc     = (float*)carve((size_t)N_NODES * DIM * 4);              // 64 MB
    u16*   qkv     = (u16*)  carve((size_t)N_NODES * QLD * 2);              // 36 MB
    u16*   Anodes  = (u16*)  carve((size_t)N_NODES * 64 * 2);               // 6.4 MB
    u16*   BstQkv  = (u16*)  carve((size_t)27 * 40 * NPQ * 8 * 2);          // 6.6 MB
    float* biasQkv = (float*)carve((size_t)27 * NPQ * 4);
    u16*   BstBig  = (u16*)  carve((size_t)3 * BIGCH * 384 * 8 * 2);        // 8.3 MB
    float* biasSkip= (float*)carve((size_t)3 * 384 * 4);
    u16*   BstW1   = (u16*)  carve((size_t)40 * 128 * 8 * 2);
    int*   cnt     = (int*)  carve((size_t)NTYP * NPAD * 4);
    int*   rowStart= (int*)  carve((size_t)NTYP * NPAD * 4);
    int*   blockSum= (int*)  carve((size_t)NTYP * 64 * 4);
    u16*   sSrc    = (u16*)  carve((size_t)NTYP * N_EDGE * 2);
    int*   sEid    = (int*)  carve((size_t)NTYP * N_EDGE * 4);
    size_t fixed = off;
    size_t bigBytes   = (size_t)NTYP * N_EDGE * EH * 2;
    size_t smallBytes = (size_t)N_EDGE * EH * 2;
    int bigEa = (ws_size >= fixed + bigBytes + (1u << 20)) ? 1 : 0;
    u16* newEa = (u16*)carve(bigEa ? bigBytes : smallBytes);

    // prep-only buffers ALIASED into hAg's hv-slot region (chunks 40+,
    // 73.6 MB; first written by k_attn long after these are consumed)
    u16* regionB = hAg + (size_t)40 * N_NODES * 8;
    u16* AqT = regionB;                       // 5.53 MB (+512-elem OOB pad)
    u16* BkT = AqT + 27 * 40 * 320 * 8 + 512;
    u16* Mb  = BkT + 27 * 40 * 320 * 8 + 512; // ends ~16.6 MB into region

    // prep
    k_convert_x<<<(N_NODES * DIM + 255) / 256, 256, 0, stream>>>(x, hAg, hNode);
    // zero pad chunks 130,131 once (beyond aliased prep buffers; attn never writes them)
    hipMemsetAsync(hAg + (size_t)130 * N_NODES * 8, 0, (size_t)2 * N_NODES * 8 * 2, stream);
    k_prep_wT<<<(27 * 40 * 320 + 255) / 256, 256, 0, stream>>>(Wq, AqT);
    k_prep_wT<<<(27 * 40 * 320 + 255) / 256, 256, 0, stream>>>(Wk, BkT);
    // M = Wq @ Wk^T via MFMA, batched over 27 (b,t)
    gemm_kernel<<<dim3(3, 3, 27), 256, 0, stream>>>(AqT, 320, BkT, nullptr,
        Mb, nullptr, 320, 320, 320, 320, 40, 0, 102400, 102400, 102400);
    k_prep_qkvW<<<(27 * 40 * NPQ + 255) / 256, 256, 0, stream>>>(Mb, BstQkv);
    k_prep_ext<<<dim3(27, 11), 256, 0, stream>>>(Wq, bq, We, be, bk, BstQkv, biasQkv);
    k_prep_qkvB<<<(27 * NPQ + 255) / 256, 256, 0, stream>>>(Wk, bq, biasQkv);
    k_prep_skipB<<<(3 * 384 + 255) / 256, 256, 0, stream>>>(bs, biasSkip);
    k_prep_bigB<<<(3 * BIGCH * 384 + 255) / 256, 256, 0, stream>>>(Ws, Wv, We, be, bv, BstBig);
    k_prep_w1W<<<(320 * 128 + 255) / 256, 256, 0, stream>>>(W1, BstW1);

    // CSR
    k_csr_zero<<<(NTYP * NPAD + 255) / 256, 256, 0, stream>>>(cnt);
    k_csr_count<<<(NTYP * N_EDGE + 255) / 256, 256, 0, stream>>>(eidx, cnt);
    k_csr_scan1<<<dim3(BPT, NTYP), 1024, 0, stream>>>(cnt, rowStart, blockSum);
    k_csr_scan2<<<1, 64, 0, stream>>>(blockSum);
    k_csr_scan3<<<(NTYP * NPAD + 255) / 256, 256, 0, stream>>>(rowStart, blockSum, cnt);
    k_csr_scatter<<<(NTYP * N_EDGE + 255) / 256, 256, 0, stream>>>(eidx, cnt, sSrc, sEid);

    const int mt = (N_NODES + 127) / 128;  // 391
    const int et = (N_EDGE + 255) / 256;
    // Anodes = x @ [W1a|W1b]
    gemm_kernel<<<dim3(1, mt), 256, 0, stream>>>(hAg, N_NODES, BstW1, nullptr,
        Anodes, nullptr, 64, 64, N_NODES, 128, 40, 0, 0, 0, 0);
    if (bigEa) {
        for (int t = 0; t < NTYP; ++t)
            k_edge_mlp<<<dim3(et), 256, 0, stream>>>(
                Anodes, eidx, eattr, W1, b1, W2, b2, newEa + (size_t)t * N_EDGE * EH, t);
    }

    // group GEMM geometry: {B chunk offset, KQ} per group g (types 2g,2g+1)
    const int gOff[5] = {0, 130, 220, 310, 400};
    const int gKQ[5]  = {132, 92, 92, 92, 48};

    for (int b = 0; b < NBLK; ++b) {
        for (int t = 0; t < NTYP; ++t) {
            int bt = b * NTYP + t;
            u16* eaT = bigEa ? (newEa + (size_t)t * N_EDGE * EH) : newEa;
            if (!bigEa)
                k_edge_mlp<<<dim3(et), 256, 0, stream>>>(
                    Anodes, eidx, eattr, W1, b1, W2, b2, eaT, t);
            gemm_kernel<<<dim3(3, mt), 256, 0, stream>>>(
                hAg, N_NODES, BstQkv + (size_t)bt * 40 * NPQ * 8, biasQkv + bt * NPQ,
                qkv, nullptr, QLD, QCOLS, N_NODES, NPQ, 40, 0, 0, 0, 0);
            k_attn<<<dim3(N_NODES / 4), 256, 0, stream>>>(
                qkv, hNode, rowStart + t * NPAD, sSrc + (size_t)t * N_EDGE,
                sEid + (size_t)t * N_EDGE, eaT, hAg, 40 + (t & 1) * 45);
            if (t & 1) {  // after odd t: reduce group (t-1)/2, freeing both slots
                int g = t >> 1;
                gemm_kernel<<<dim3(3, mt), 256, 0, stream>>>(
                    (g == 0) ? hAg : regionB, N_NODES,
                    BstBig + ((size_t)b * BIGCH + gOff[g]) * 384 * 8,
                    (g == 0) ? (biasSkip + b * 384) : nullptr,
                    nullptr, acc, DIM, DIM, N_NODES, 384, gKQ[g],
                    (g == 0) ? 1 : 2, 0, 0, 0);
            }
        }
        // last group: type 8 alone (slot 0); tail KQ pad hits zeroed B chunks
        gemm_kernel<<<dim3(3, mt), 256, 0, stream>>>(
            regionB, N_NODES, BstBig + ((size_t)b * BIGCH + gOff[4]) * 384 * 8, nullptr,
            nullptr, acc, DIM, DIM, N_NODES, 384, gKQ[4], 2, 0, 0, 0);
        k_post<<<N_GRAPH, 1024, 0, stream>>>(acc, hAg, hNode, batch,
                                             gamma + b * DIM, beta + b * DIM);
    }
    k_maxpool<<<N_GRAPH, 320, 0, stream>>>(hAg, batch, out);
}

// Round 6
// 5415.794 us; speedup vs baseline: 1.1719x; 1.0198x over previous
//
#include <hip/hip_runtime.h>

#define N_NODES 50000
#define N_EDGE  150000
#define N_GRAPH 200
#define DIM     320
#define EDI     15
#define EH      32
#define NBLK    3
#define NTYP    9
#define NPAD    51200   // per-type CSR stride (50 blocks of 1024)
#define BPT     50      // scan blocks per type
#define QLD     360     // qkv' row stride (353 used cols), 16B-aligned rows
#define QCOLS   353     // q''(0-319) | qw(320-351) | qwbe(352)
#define NPQ     384     // qkv' GEMM N padded to 3 tiles of 128
// hAg layout (kq-major chunks of 8 k x N_NODES x 8 u16):
//   chunks 0-39 : h (DIM=320), then nslots x 45-chunk hv|s|flag slots.
//   nslots=2: +2 zero-pad chunks (130,131) -> 132 chunks total
//   nslots=4: 220 chunks, no pads (group K's line up exactly)
// BstBig keeps the FULL 448-chunk K layout; group GEMMs index into it:
//   nslots=2: g0{0,132,m1} g1{130,92,m2} g2{220,92} g3{310,92} g4{400,48}
//   nslots=4: g0{0,220,m1} g1{220,180,m2} g2{400,48,m2}
#define BIGCH   448

typedef unsigned short u16;
typedef unsigned int   u32;
typedef __bf16 bf16x8 __attribute__((ext_vector_type(8)));
typedef float  f32x4  __attribute__((ext_vector_type(4)));

__device__ __forceinline__ float b2f(u16 s) {
    u32 u = ((u32)s) << 16;
    return __builtin_bit_cast(float, u);
}
__device__ __forceinline__ float b2f_lo(u32 u) { return __builtin_bit_cast(float, u << 16); }
__device__ __forceinline__ float b2f_hi(u32 u) { return __builtin_bit_cast(float, u & 0xffff0000u); }
__device__ __forceinline__ u16 f2b(float f) {
    u32 u = __builtin_bit_cast(u32, f);
    u = (u + 0x7fffu + ((u >> 16) & 1u)) >> 16;
    return (u16)u;
}

// global -> LDS direct DMA, 16 B per lane. LDS dest = m0 + lane*16 (wave-uniform
// base), global src per-lane. Untracked by compiler => explicit asm vmcnt waits.
__device__ __forceinline__ void gll16(const u16* g, u32 ldsAddr) {
    u32 m0v = (u32)__builtin_amdgcn_readfirstlane((int)ldsAddr);
    asm volatile("s_mov_b32 m0, %0\n\t"
                 "global_load_lds_dwordx4 %1, off"
                 :: "s"(m0v), "v"((unsigned long long)(size_t)g)
                 : "memory");
}

// ---------------------------------------------------------------------------
// bf16 MFMA GEMM — LDS-staged, 3-buffer 2-deep pipeline with COUNTED vmcnt
// (T4): stage(s+2) issued each iter, wait vmcnt(4) keeps its 4 loads in
// flight across the barrier (never drain to 0 mid-loop). T1 XCD swizzle.
// Inputs kq-major: element (k,m) at ((k>>3)*Stride + m)*8 + (k&7).
// Tile 128x128, BK=32, 4 waves of 64x64. mode 0: Cb=bf16 ; 1: Cf=f32 ; 2: +=
// ---------------------------------------------------------------------------
__global__ __launch_bounds__(256) void gemm_kernel(
    const u16* __restrict__ A, int Mstride,
    const u16* __restrict__ Bst, const float* __restrict__ bias,
    u16* __restrict__ Cb, float* __restrict__ Cf,
    int ldc, int out_cols, int M, int NP, int KQ, int mode,
    int zA, int zB, int zC)
{
    A += (size_t)blockIdx.z * zA;
    Bst += (size_t)blockIdx.z * zB;
    if (Cb) Cb += (size_t)blockIdx.z * zC;
    if (Cf) Cf += (size_t)blockIdx.z * zC;

    const int tid = threadIdx.x;
    const int wave = tid >> 6, lane = tid & 63;

    // XCD swizzle (bijective): XCD x gets a contiguous logical range
    const int nwg = gridDim.x * gridDim.y;
    const int flat = blockIdx.y * gridDim.x + blockIdx.x;
    const int qq = nwg >> 3, rr = nwg & 7;
    const int xcd = flat & 7, loc = flat >> 3;
    const int swz = (xcd < rr ? xcd * (qq + 1) : rr * (qq + 1) + (xcd - rr) * qq) + loc;
    const int n0 = (swz % gridDim.x) * 128, m0 = (swz / gridDim.x) * 128;

    const int wm = (wave & 1) << 6, wn = (wave >> 1) << 6;
    const int lm = lane & 15, quad = lane >> 4;

    // [buf(3)][A/B][chunk(4)][node(128)] of 16B slots = 48 KB
    __shared__ uint4 smem[3][2][512];
    const u32 ldsBase = (u32)(size_t)&smem[0][0][0];

    f32x4 acc[4][4] = {};
    const int nIter = KQ >> 2;   // K-steps of 32 (4 chunks of 8)

    auto stage = [&](int s, int buf) {
        const int c0 = s << 2;
        const u32 bufBase = ldsBase + (u32)buf * 16384u;
#pragma unroll
        for (int u = 0; u < 2; ++u) {
            const int i = wave + (u << 2);
            const int chunk = i >> 1, half = (i & 1) << 6;
            const u16* ga = A + ((size_t)(c0 + chunk) * Mstride + m0 + half + lane) * 8;
            gll16(ga, bufBase + (u32)i * 1024u);
            const u16* gb = Bst + ((size_t)(c0 + chunk) * NP + n0 + half + lane) * 8;
            gll16(gb, bufBase + 8192u + (u32)i * 1024u);
        }
    };

    // prologue: 2 stages in flight, wait only the first
    stage(0, 0);
    if (nIter > 1) {
        stage(1, 1);
        asm volatile("s_waitcnt vmcnt(4)" ::: "memory");
    } else {
        asm volatile("s_waitcnt vmcnt(0)" ::: "memory");
    }
    __syncthreads();

    int bRd = 0, bIss = 2;
    for (int s = 0; s < nIter; ++s) {
        const bool more = (s + 2 < nIter);
        if (more) { stage(s + 2, bIss); bIss = (bIss == 2) ? 0 : bIss + 1; }
        const uint4* aT = &smem[bRd][0][0];
        const uint4* bT = &smem[bRd][1][0];
        bf16x8 af[4], bfr[4];
#pragma unroll
        for (int mi = 0; mi < 4; ++mi)
            af[mi] = __builtin_bit_cast(bf16x8, aT[quad * 128 + wm + mi * 16 + lm]);
#pragma unroll
        for (int ni = 0; ni < 4; ++ni)
            bfr[ni] = __builtin_bit_cast(bf16x8, bT[quad * 128 + wn + ni * 16 + lm]);
#pragma unroll
        for (int mi = 0; mi < 4; ++mi)
#pragma unroll
            for (int ni = 0; ni < 4; ++ni)
                acc[mi][ni] = __builtin_amdgcn_mfma_f32_16x16x32_bf16(af[mi], bfr[ni], acc[mi][ni], 0, 0, 0);
        if (s + 1 < nIter) {
            // wait stage(s+1) complete; stage(s+2)'s 4 loads stay in flight
            if (more) asm volatile("s_waitcnt vmcnt(4)" ::: "memory");
            else      asm volatile("s_waitcnt vmcnt(0)" ::: "memory");
            __syncthreads();
        }
        bRd = (bRd == 2) ? 0 : bRd + 1;
    }

    // epilogue: C/D layout col=lane&15, row=quad*4+reg
#pragma unroll
    for (int mi = 0; mi < 4; ++mi) {
        int row = m0 + wm + mi * 16 + quad * 4;
#pragma unroll
        for (int ni = 0; ni < 4; ++ni) {
            int col = n0 + wn + ni * 16 + lm;
            float bv = bias ? bias[col] : 0.f;
#pragma unroll
            for (int r = 0; r < 4; ++r) {
                int rr2 = row + r;
                if (rr2 < M && col < out_cols) {
                    float v = acc[mi][ni][r] + bv;
                    size_t off = (size_t)rr2 * ldc + col;
                    if (mode == 0)      Cb[off] = f2b(v);
                    else if (mode == 1) Cf[off] = v;
                    else                Cf[off] += v;
                }
            }
        }
    }
}

// ---------------------------------------------------------------------------
// prep kernels
// ---------------------------------------------------------------------------
__global__ void k_convert_x(const float* __restrict__ x, u16* __restrict__ hb,
                            u16* __restrict__ hNode) {
    int i = blockIdx.x * 256 + threadIdx.x;
    if (i >= N_NODES * DIM) return;
    int node = i / DIM, c = i - node * DIM;
    u16 v = f2b(x[i]);
    hb[((size_t)(c >> 3) * N_NODES + node) * 8 + (c & 7)] = v;
    hNode[i] = v;
}

// W [27][320][320] f32 -> kq-major bf16 over contraction j:
// T[((bt*40 + (j>>3))*320 + e)*8 + (j&7)] = W[(bt*320+e)*320 + j]
__global__ void k_prep_wT(const float* __restrict__ W, u16* __restrict__ T) {
    int i = blockIdx.x * 256 + threadIdx.x;
    if (i >= 27 * 40 * 320) return;
    int e = i % 320, jq = (i / 320) % 40, bt = i / (320 * 40);
    const float* src = W + ((size_t)bt * 320 + e) * 320 + jq * 8;
    u16 tmp[8];
#pragma unroll
    for (int r = 0; r < 8; ++r) tmp[r] = f2b(src[r]);
    *(uint4*)(&T[(((size_t)bt * 40 + jq) * 320 + e) * 8]) = *(uint4*)tmp;
}

// Bst_qkv cols 0-319 = M=WqWk^T (bf16, from Mb), >=353 zero. uint4 writes.
__global__ void k_prep_qkvW(const u16* __restrict__ Mb, u16* __restrict__ Bst) {
    int i = blockIdx.x * 256 + threadIdx.x;
    if (i >= 27 * 40 * NPQ) return;
    int col = i % NPQ, kq = (i / NPQ) % 40, bt = i / (NPQ * 40);
    if (col >= 320 && col < QCOLS) return;  // ext cols written by k_prep_ext
    u16 tmp[8];
    if (col >= QCOLS) {
#pragma unroll
        for (int r = 0; r < 8; ++r) tmp[r] = 0;
    } else {
#pragma unroll
        for (int r = 0; r < 8; ++r)
            tmp[r] = Mb[((size_t)bt * 320 + kq * 8 + r) * 320 + col];
    }
    *(uint4*)(&Bst[(((size_t)bt * 40 + kq) * NPQ + col) * 8]) = *(uint4*)tmp;
}

// ext columns: 320+c = (Wq@We^T) c<32 ; 352 = Wq@(be+bk) ; bias from bq
__global__ __launch_bounds__(256) void k_prep_ext(
    const float* __restrict__ Wq, const float* __restrict__ bq,
    const float* __restrict__ We, const float* __restrict__ be,
    const float* __restrict__ bk,
    u16* __restrict__ Bst, float* __restrict__ biasQkv)
{
    __shared__ float WeL[33 * 321];
    int bt = blockIdx.x, kt = blockIdx.y;  // kt 0..10
    for (int i = threadIdx.x; i < 33 * 320; i += 256) {
        int r = i / 320, d = i - r * 320;
        WeL[r * 321 + d] = (r < 32) ? We[((size_t)bt * 32 + r) * 320 + d]
                                    : (be[(size_t)bt * 320 + d] + bk[(size_t)bt * 320 + d]);
    }
    __syncthreads();
    if (kt < 10) {
        int k  = kt * 32 + (threadIdx.x >> 3);
        int ct = threadIdx.x & 7;
        const float* wq = Wq + ((size_t)bt * 320 + k) * 320;
        float dot[5] = {0.f, 0.f, 0.f, 0.f, 0.f};
        for (int d = 0; d < 320; ++d) {
            float w = wq[d];
            dot[0] += w * WeL[ct * 321 + d];
            dot[1] += w * WeL[(ct + 8) * 321 + d];
            dot[2] += w * WeL[(ct + 16) * 321 + d];
            dot[3] += w * WeL[(ct + 24) * 321 + d];
            dot[4] += w * WeL[32 * 321 + d];
        }
#pragma unroll
        for (int u = 0; u < 4; ++u)
            Bst[(((size_t)bt * 40 + (k >> 3)) * NPQ + 320 + ct + u * 8) * 8 + (k & 7)] = f2b(dot[u]);
        if (ct == 0)
            Bst[(((size_t)bt * 40 + (k >> 3)) * NPQ + 352) * 8 + (k & 7)] = f2b(dot[4]);
    } else {
        int c = threadIdx.x;
        if (c < 33) {
            const float* b = bq + (size_t)bt * 320;
            float s = 0.f;
            for (int d = 0; d < 320; ++d) s += b[d] * WeL[c * 321 + d];
            biasQkv[bt * NPQ + 320 + c] = s;
        }
    }
}

// bias cols 0-319 = Wk @ bq (per-row dot), 353-383 zero (320-352 from ext)
__global__ __launch_bounds__(256) void k_prep_qkvB(
    const float* __restrict__ Wk, const float* __restrict__ bq,
    float* __restrict__ bias)
{
    int i = blockIdx.x * 256 + threadIdx.x;
    if (i >= 27 * NPQ) return;
    int col = i % NPQ, bt = i / NPQ;
    if (col < 320) {
        const float4* wr = (const float4*)(Wk + ((size_t)bt * 320 + col) * 320);
        const float4* bb = (const float4*)(bq + (size_t)bt * 320);
        float s = 0.f;
        for (int j = 0; j < 80; ++j) {
            float4 a = wr[j], b = bb[j];
            s += a.x * b.x + a.y * b.y + a.z * b.z + a.w * b.w;
        }
        bias[bt * NPQ + col] = s;
    } else if (col >= QCOLS) {
        bias[bt * NPQ + col] = 0.f;
    }
}

__global__ void k_prep_skipB(const float* __restrict__ bs, float* __restrict__ bias) {
    int i = blockIdx.x * 256 + threadIdx.x;
    if (i >= 3 * 384) return;
    int col = i % 384, b = i / 384;
    float v = 0.f;
    if (col < 320)
        for (int t = 0; t < 9; ++t) v += bs[(b * 9 + t) * 320 + col];
    bias[i] = v;
}

// Big-GEMM B: [3][448 chunks][384][8]. k<320: sum_t Ws ; else per type t
// (360 k each): kl<320 -> Wv[b,t][kl], kl<352 -> We[b,t][kl-320],
// kl==352 -> be+bv (flag row), else 0. col>=320 -> 0. Chunks 445-447 zero.
__global__ void k_prep_bigB(const float* __restrict__ Ws, const float* __restrict__ Wv,
                            const float* __restrict__ We, const float* __restrict__ be,
                            const float* __restrict__ bv, u16* __restrict__ Bst) {
    int i = blockIdx.x * 256 + threadIdx.x;
    if (i >= 3 * BIGCH * 384) return;
    int col = i % 384, q = (i / 384) % BIGCH, b = i / (384 * BIGCH);
    u16 tmp[8];
#pragma unroll
    for (int r = 0; r < 8; ++r) {
        int k = q * 8 + r;
        float v = 0.f;
        if (col < 320) {
            if (k < 320) {
                for (int t = 0; t < 9; ++t)
                    v += Ws[((size_t)(b * 9 + t) * 320 + k) * 320 + col];
            } else {
                int kk = k - 320, t = kk / 360, kl = kk - t * 360;
                if (t < 9) {
                    int bt = b * 9 + t;
                    if (kl < 320)       v = Wv[((size_t)bt * 320 + kl) * 320 + col];
                    else if (kl < 352)  v = We[((size_t)bt * 32 + (kl - 320)) * 320 + col];
                    else if (kl == 352) v = be[(size_t)bt * 320 + col] + bv[(size_t)bt * 320 + col];
                }
            }
        }
        tmp[r] = f2b(v);
    }
    *(uint4*)(&Bst[(((size_t)b * BIGCH + q) * 384 + col) * 8]) = *(uint4*)tmp;
}

__global__ void k_prep_w1W(const float* __restrict__ W1, u16* __restrict__ Bst) {
    int i = blockIdx.x * 256 + threadIdx.x;
    if (i >= 320 * 128) return;
    int col = i & 127, k = i >> 7;
    float v = 0.f;
    if (col < 32)      v = W1[(size_t)k * 32 + col];
    else if (col < 64) v = W1[(size_t)(320 + k) * 32 + (col - 32)];
    Bst[((size_t)(k >> 3) * 128 + col) * 8 + (k & 7)] = f2b(v);
}

// ---------------------------------------------------------------------------
// CSR build
// ---------------------------------------------------------------------------
__global__ void k_csr_zero(int* __restrict__ cnt) {
    int i = blockIdx.x * 256 + threadIdx.x;
    if (i < NTYP * NPAD) cnt[i] = 0;
}
__global__ void k_csr_count(const int* __restrict__ eidx, int* __restrict__ cnt) {
    int i = blockIdx.x * 256 + threadIdx.x;
    if (i >= NTYP * N_EDGE) return;
    int t = i / N_EDGE, e = i - t * N_EDGE;
    int dst = eidx[(size_t)(t * 2 + 1) * N_EDGE + e];
    atomicAdd(&cnt[t * NPAD + dst], 1);
}
__global__ __launch_bounds__(1024) void k_csr_scan1(const int* __restrict__ cnt,
                                                    int* __restrict__ rowStart,
                                                    int* __restrict__ blockSum) {
    __shared__ int tmp[1024];
    int t = blockIdx.y, blk = blockIdx.x, tid = threadIdx.x;
    int idx = t * NPAD + blk * 1024 + tid;
    int v = cnt[idx];
    tmp[tid] = v;
    __syncthreads();
    for (int off = 1; off < 1024; off <<= 1) {
        int x = (tid >= off) ? tmp[tid - off] : 0;
        __syncthreads();
        tmp[tid] += x;
        __syncthreads();
    }
    rowStart[idx] = tmp[tid] - v;
    if (tid == 1023) blockSum[t * 64 + blk] = tmp[tid];
}
__global__ void k_csr_scan2(int* __restrict__ blockSum) {
    int t = threadIdx.x;
    if (t >= NTYP) return;
    int run = 0;
    for (int b = 0; b < BPT; ++b) {
        int v = blockSum[t * 64 + b];
        blockSum[t * 64 + b] = run;
        run += v;
    }
}
__global__ void k_csr_scan3(int* __restrict__ rowStart, const int* __restrict__ blockSum,
                            int* __restrict__ cursor) {
    int i = blockIdx.x * 256 + threadIdx.x;
    if (i >= NTYP * NPAD) return;
    int t = i / NPAD, n = i - t * NPAD;
    int v = rowStart[i] + blockSum[t * 64 + (n >> 10)];
    rowStart[i] = v;
    cursor[i] = v;
}
__global__ void k_csr_scatter(const int* __restrict__ eidx, int* __restrict__ cursor,
                              u16* __restrict__ sSrc, int* __restrict__ sEid) {
    int i = blockIdx.x * 256 + threadIdx.x;
    if (i >= NTYP * N_EDGE) return;
    int t = i / N_EDGE, e = i - t * N_EDGE;
    int src = eidx[(size_t)(t * 2) * N_EDGE + e];
    int dst = eidx[(size_t)(t * 2 + 1) * N_EDGE + e];
    int pos = atomicAdd(&cursor[t * NPAD + dst], 1);
    sSrc[(size_t)t * N_EDGE + pos] = (u16)src;
    sEid[(size_t)t * N_EDGE + pos] = e;
}

// ---------------------------------------------------------------------------
// Edge MLP for one type t
// ---------------------------------------------------------------------------
__global__ __launch_bounds__(256) void k_edge_mlp(
    const u16* __restrict__ Anodes, const int* __restrict__ eidx,
    const float* __restrict__ eattr, const float* __restrict__ W1,
    const float* __restrict__ b1, const float* __restrict__ W2,
    const float* __restrict__ b2, u16* __restrict__ outEa, int t)
{
    __shared__ float w1c[EDI][EH];
    __shared__ float w2s[EH][EH];
    __shared__ float b1s[EH], b2s[EH];
    int tid = threadIdx.x;
    for (int i = tid; i < EDI * EH; i += 256) w1c[i / EH][i % EH] = W1[(640 + i / EH) * EH + (i % EH)];
    for (int i = tid; i < EH * EH; i += 256) w2s[i / EH][i % EH] = W2[i];
    if (tid < EH) { b1s[tid] = b1[tid]; b2s[tid] = b2[tid]; }
    __syncthreads();

    int e = blockIdx.x * 256 + tid;
    if (e >= N_EDGE) return;
    int src = eidx[(size_t)(t * 2) * N_EDGE + e];
    int dst = eidx[(size_t)(t * 2 + 1) * N_EDGE + e];
    const float* eat = eattr + ((size_t)t * N_EDGE + e) * EDI;
    const u16* a1 = Anodes + (size_t)src * 64;
    const u16* a2 = Anodes + (size_t)dst * 64 + 32;

    float h1[EH];
#pragma unroll
    for (int j = 0; j < EH; ++j) h1[j] = b2f(a1[j]) + b2f(a2[j]) + b1s[j];
    for (int i = 0; i < EDI; ++i) {
        float v = eat[i];
#pragma unroll
        for (int j = 0; j < EH; ++j) h1[j] += v * w1c[i][j];
    }
#pragma unroll
    for (int j = 0; j < EH; ++j) h1[j] = h1[j] > 0.f ? h1[j] : 0.01f * h1[j];

    u16* orow = outEa + (size_t)e * EH;
    for (int j = 0; j < EH; ++j) {
        float o = b2s[j];
#pragma unroll
        for (int i = 0; i < EH; ++i) o += h1[i] * w2s[i][j];
        orow[j] = f2b(o);
    }
}

// ---------------------------------------------------------------------------
// Attention, v-folded: score = (q''[dst].h[src] + qw.ea + qwbe)/sqrt(D).
// Aggregates hv = sum p*h[src]/l IN h-SPACE (reusing the loaded h values);
// Wv applied later by the group GEMMs (sum w = 1 => v-proj commutes).
// Writes hv(320)+s(32)+flag into hAg chunks [cb .. cb+44].
// Empty nodes write zero rows (flag 0 gates be+bv).
// ---------------------------------------------------------------------------
__global__ __launch_bounds__(256) void k_attn(
    const u16* __restrict__ qkv, const u16* __restrict__ hNode,
    const int* __restrict__ rowStart,
    const u16* __restrict__ sSrc, const int* __restrict__ sEid,
    const u16* __restrict__ ea, u16* __restrict__ hA, int cb)
{
    int wave = threadIdx.x >> 6, lane = threadIdx.x & 63;
    int n = blockIdx.x * 4 + wave;
    if (n >= N_NODES) return;
    int eb = rowStart[n], ee = rowStart[n + 1];

    float l = 0.f, as = 0.f;
    float av0 = 0.f, av1 = 0.f, av2 = 0.f, av3 = 0.f, avt = 0.f;

    if (eb != ee) {
        const u16* qrow = qkv + (size_t)n * QLD;
        uint2 qv = *(const uint2*)(qrow + 4 * lane);
        float q40 = b2f_lo(qv.x), q41 = b2f_hi(qv.x);
        float q42 = b2f_lo(qv.y), q43 = b2f_hi(qv.y);
        float q1 = b2f(qrow[256 + lane]);
        float qwl = (lane < 33) ? b2f(qrow[320 + lane]) : 0.f;
        float qwbe = __shfl(qwl, 32, 64);
        float qw = (lane < 32) ? qwl : 0.f;
        const float RS = 0.05590169943749474f;  // 1/sqrt(320)
        float m = -INFINITY;

        int ei = eb;
        for (; ei + 2 <= ee; ei += 2) {
            int s0 = sSrc[ei], s1 = sSrc[ei + 1];
            int id0 = sEid[ei], id1 = sEid[ei + 1];
            const u16* kr0 = hNode + (size_t)s0 * DIM;
            const u16* kr1 = hNode + (size_t)s1 * DIM;
            uint2 k0v = *(const uint2*)(kr0 + 4 * lane);
            uint2 k1v = *(const uint2*)(kr1 + 4 * lane);
            float k00 = b2f_lo(k0v.x), k01 = b2f_hi(k0v.x);
            float k02 = b2f_lo(k0v.y), k03 = b2f_hi(k0v.y);
            float k10 = b2f_lo(k1v.x), k11 = b2f_hi(k1v.x);
            float k12 = b2f_lo(k1v.y), k13 = b2f_hi(k1v.y);
            float k0t = b2f(kr0[256 + lane]);
            float k1t = b2f(kr1[256 + lane]);
            float ea0 = (lane < 32) ? b2f(ea[(size_t)id0 * 32 + lane]) : 0.f;
            float ea1 = (lane < 32) ? b2f(ea[(size_t)id1 * 32 + lane]) : 0.f;
            float d0 = qw * ea0 + q1 * k0t + q40 * k00 + q41 * k01 + q42 * k02 + q43 * k03;
            float d1 = qw * ea1 + q1 * k1t + q40 * k10 + q41 * k11 + q42 * k12 + q43 * k13;
#pragma unroll
            for (int off = 32; off > 0; off >>= 1) {
                d0 += __shfl_xor(d0, off, 64);
                d1 += __shfl_xor(d1, off, 64);
            }
            float a0 = (d0 + qwbe) * RS, a1 = (d1 + qwbe) * RS;
            float mn = fmaxf(m, fmaxf(a0, a1));
            float sc = __expf(m - mn);
            float p0 = __expf(a0 - mn), p1 = __expf(a1 - mn);
            l = l * sc + p0 + p1;
            av0 = av0 * sc + p0 * k00 + p1 * k10;
            av1 = av1 * sc + p0 * k01 + p1 * k11;
            av2 = av2 * sc + p0 * k02 + p1 * k12;
            av3 = av3 * sc + p0 * k03 + p1 * k13;
            avt = avt * sc + p0 * k0t + p1 * k1t;
            as = as * sc + p0 * ea0 + p1 * ea1;
            m = mn;
        }
        if (ei < ee) {
            int s0 = sSrc[ei];
            int id0 = sEid[ei];
            const u16* kr0 = hNode + (size_t)s0 * DIM;
            uint2 k0v = *(const uint2*)(kr0 + 4 * lane);
            float k00 = b2f_lo(k0v.x), k01 = b2f_hi(k0v.x);
            float k02 = b2f_lo(k0v.y), k03 = b2f_hi(k0v.y);
            float k0t = b2f(kr0[256 + lane]);
            float ea0 = (lane < 32) ? b2f(ea[(size_t)id0 * 32 + lane]) : 0.f;
            float d0 = qw * ea0 + q1 * k0t + q40 * k00 + q41 * k01 + q42 * k02 + q43 * k03;
#pragma unroll
            for (int off = 32; off > 0; off >>= 1) d0 += __shfl_xor(d0, off, 64);
            float a0 = (d0 + qwbe) * RS;
            float mn = fmaxf(m, a0);
            float sc = __expf(m - mn), p0 = __expf(a0 - mn);
            l = l * sc + p0;
            av0 = av0 * sc + p0 * k00;
            av1 = av1 * sc + p0 * k01;
            av2 = av2 * sc + p0 * k02;
            av3 = av3 * sc + p0 * k03;
            avt = avt * sc + p0 * k0t;
            as = as * sc + p0 * ea0;
        }
    }

    float inv = (l > 0.f) ? 1.f / l : 0.f;
    // hv cols 4l..4l+3 -> chunk cb+(l>>1), offset (l&1)*4 (8B store)
    u32 w0 = (u32)f2b(av0 * inv) | ((u32)f2b(av1 * inv) << 16);
    u32 w1 = (u32)f2b(av2 * inv) | ((u32)f2b(av3 * inv) << 16);
    uint2 wv; wv.x = w0; wv.y = w1;
    *(uint2*)(hA + ((size_t)(cb + (lane >> 1)) * N_NODES + n) * 8 + (lane & 1) * 4) = wv;
    // hv col 256+l
    hA[((size_t)(cb + 32 + (lane >> 3)) * N_NODES + n) * 8 + (lane & 7)] = f2b(avt * inv);
    if (lane < 32) {
        hA[((size_t)(cb + 40 + (lane >> 3)) * N_NODES + n) * 8 + (lane & 7)] = f2b(as * inv);
    } else if (lane == 32) {
        uint4 fz; fz.x = (eb != ee) ? 0x3f80u : 0u; fz.y = 0u; fz.z = 0u; fz.w = 0u;
        *(uint4*)(hA + ((size_t)(cb + 44) * N_NODES + n) * 8) = fz;  // flag + zero pad
    }
}

// ---------------------------------------------------------------------------
// Post: x_ = lrelu(acc/9); graph layernorm; h = 0.5*(h + x_)
// maintains BOTH kq-major hAg[0:40] (GEMM A) and node-major hNode (attn gather)
// ---------------------------------------------------------------------------
__device__ __forceinline__ int lowerb(const int* a, int n, int v) {
    int lo = 0, hi = n;
    while (lo < hi) { int mid = (lo + hi) >> 1; if (a[mid] < v) lo = mid + 1; else hi = mid; }
    return lo;
}

__global__ __launch_bounds__(1024) void k_post(
    const float* __restrict__ acc, u16* __restrict__ hb, u16* __restrict__ hNode,
    const int* __restrict__ batch, const float* __restrict__ gamma,
    const float* __restrict__ beta)
{
    int g = blockIdx.x;
    int start = lowerb(batch, N_NODES, g);
    int end   = lowerb(batch, N_NODES, g + 1);
    int cnt = end - start;
    if (cnt == 0) return;
    int i0 = start * DIM, i1 = end * DIM;

    float s = 0.f, ss = 0.f;
    for (int i = i0 + threadIdx.x; i < i1; i += 1024) {
        float v = acc[i] * (1.f / 9.f);
        v = v > 0.f ? v : 0.01f * v;
        s += v; ss += v * v;
    }
    __shared__ float rs[16], rss[16];
#pragma unroll
    for (int off = 32; off > 0; off >>= 1) { s += __shfl_xor(s, off, 64); ss += __shfl_xor(ss, off, 64); }
    int wave = threadIdx.x >> 6, lane = threadIdx.x & 63;
    if (lane == 0) { rs[wave] = s; rss[wave] = ss; }
    __syncthreads();
    if (threadIdx.x == 0) {
        float S = 0.f, SS = 0.f;
        for (int w = 0; w < 16; ++w) { S += rs[w]; SS += rss[w]; }
        float norm = (float)cnt * DIM;
        float mean = S / norm;
        float var = SS / norm - mean * mean;
        rs[0] = mean;
        rss[0] = rsqrtf(var + 1e-5f);
    }
    __syncthreads();
    float mean = rs[0], rsig = rss[0];
    for (int i = i0 + threadIdx.x; i < i1; i += 1024) {
        float v = acc[i] * (1.f / 9.f);
        v = v > 0.f ? v : 0.01f * v;
        int node = i / DIM, c = i - node * DIM;
        float o = (v - mean) * rsig * gamma[c] + beta[c];
        u16 nb = f2b(0.5f * (b2f(hNode[i]) + o));
        hNode[i] = nb;
        hb[((size_t)(c >> 3) * N_NODES + node) * 8 + (c & 7)] = nb;
    }
}

__global__ __launch_bounds__(320) void k_maxpool(
    const u16* __restrict__ hb, const int* __restrict__ batch, float* __restrict__ out)
{
    int g = blockIdx.x, c = threadIdx.x;
    int start = lowerb(batch, N_NODES, g);
    int end   = lowerb(batch, N_NODES, g + 1);
    size_t base = (size_t)(c >> 3) * N_NODES * 8 + (c & 7);
    float m = -INFINITY;
    for (int n = start; n < end; ++n) m = fmaxf(m, b2f(hb[base + (size_t)n * 8]));
    out[(size_t)g * DIM + c] = m;
}

// ---------------------------------------------------------------------------
extern "C" void kernel_launch(void* const* d_in, const int* in_sizes, int n_in,
                              void* d_out, int out_size, void* d_ws, size_t ws_size,
                              hipStream_t stream)
{
    (void)in_sizes; (void)n_in; (void)out_size;
    const float* x     = (const float*)d_in[0];
    const int*   batch = (const int*)d_in[1];
    const int*   eidx  = (const int*)d_in[2];
    const float* eattr = (const float*)d_in[3];
    const float* W1 = (const float*)d_in[4];
    const float* b1 = (const float*)d_in[5];
    const float* W2 = (const float*)d_in[6];
    const float* b2 = (const float*)d_in[7];
    const float* Wq = (const float*)d_in[8];
    const float* bq = (const float*)d_in[9];
    const float* Wk = (const float*)d_in[10];
    const float* bk = (const float*)d_in[11];
    const float* Wv = (const float*)d_in[12];
    const float* bv = (const float*)d_in[13];
    const float* We = (const float*)d_in[14];
    const float* be = (const float*)d_in[15];
    const float* Ws = (const float*)d_in[16];
    const float* bs = (const float*)d_in[17];
    const float* gamma = (const float*)d_in[18];
    const float* beta  = (const float*)d_in[19];
    float* out = (float*)d_out;

    auto al = [](size_t b) -> size_t { return (b + 255) & ~(size_t)255; };
    // everything except hAg and newEa
    const size_t szOther =
        al((size_t)N_NODES * DIM * 2)        // hNode
      + al((size_t)N_NODES * DIM * 4)        // acc
      + al((size_t)N_NODES * QLD * 2)        // qkv
      + al((size_t)N_NODES * 64 * 2)         // Anodes
      + al((size_t)27 * 40 * NPQ * 8 * 2)    // BstQkv
      + al((size_t)27 * NPQ * 4)             // biasQkv
      + al((size_t)3 * BIGCH * 384 * 8 * 2)  // BstBig
      + al((size_t)3 * 384 * 4)              // biasSkip
      + al((size_t)40 * 128 * 8 * 2)         // BstW1
      + al((size_t)NTYP * NPAD * 4) * 2      // cnt, rowStart
      + al((size_t)NTYP * 64 * 4)            // blockSum
      + al((size_t)NTYP * N_EDGE * 2)        // sSrc
      + al((size_t)NTYP * N_EDGE * 4);       // sEid
    const size_t hag2 = al((size_t)132 * N_NODES * 8 * 2 + 1024);
    const size_t hag4 = al((size_t)220 * N_NODES * 8 * 2 + 1024);
    const size_t bigB = (size_t)NTYP * N_EDGE * EH * 2;
    const size_t smlB = (size_t)N_EDGE * EH * 2;
    const size_t mar = 1u << 20;
    int nslots, bigEa;
    if      (ws_size >= hag4 + szOther + bigB + mar) { nslots = 4; bigEa = 1; }
    else if (ws_size >= hag2 + szOther + bigB + mar) { nslots = 2; bigEa = 1; }
    else if (ws_size >= hag4 + szOther + smlB + mar) { nslots = 4; bigEa = 0; }
    else                                             { nslots = 2; bigEa = 0; }
    const int hagch = (nslots == 4) ? 220 : 132;

    char* base = (char*)d_ws;
    size_t off = 0;
    auto carve = [&](size_t bytes) -> char* {
        char* r = base + off;
        off += (bytes + 255) & ~(size_t)255;
        return r;
    };
    u16*   hAg     = (u16*)  carve((size_t)hagch * N_NODES * 8 * 2 + 1024);
    u16*   hNode   = (u16*)  carve((size_t)N_NODES * DIM * 2);
    float* acc     = (float*)carve((size_t)N_NODES * DIM * 4);
    u16*   qkv     = (u16*)  carve((size_t)N_NODES * QLD * 2);
    u16*   Anodes  = (u16*)  carve((size_t)N_NODES * 64 * 2);
    u16*   BstQkv  = (u16*)  carve((size_t)27 * 40 * NPQ * 8 * 2);
    float* biasQkv = (float*)carve((size_t)27 * NPQ * 4);
    u16*   BstBig  = (u16*)  carve((size_t)3 * BIGCH * 384 * 8 * 2);
    float* biasSkip= (float*)carve((size_t)3 * 384 * 4);
    u16*   BstW1   = (u16*)  carve((size_t)40 * 128 * 8 * 2);
    int*   cnt     = (int*)  carve((size_t)NTYP * NPAD * 4);
    int*   rowStart= (int*)  carve((size_t)NTYP * NPAD * 4);
    int*   blockSum= (int*)  carve((size_t)NTYP * 64 * 4);
    u16*   sSrc    = (u16*)  carve((size_t)NTYP * N_EDGE * 2);
    int*   sEid    = (int*)  carve((size_t)NTYP * N_EDGE * 4);
    u16*   newEa   = (u16*)  carve(bigEa ? bigB : smlB);

    // prep-only buffers ALIASED into hAg's hv-slot region (chunks 40+;
    // first written by k_attn long after these are consumed)
    u16* regionB = hAg + (size_t)40 * N_NODES * 8;
    u16* AqT = regionB;                       // 5.53 MB (+512-elem pad)
    u16* BkT = AqT + 27 * 40 * 320 * 8 + 512;
    u16* Mb  = BkT + 27 * 40 * 320 * 8 + 512; // ends ~16.6 MB into region

    // prep
    k_convert_x<<<(N_NODES * DIM + 255) / 256, 256, 0, stream>>>(x, hAg, hNode);
    if (nslots == 2)  // zero pad chunks 130,131 (beyond aliased prep buffers)
        hipMemsetAsync(hAg + (size_t)130 * N_NODES * 8, 0, (size_t)2 * N_NODES * 8 * 2, stream);
    k_prep_wT<<<(27 * 40 * 320 + 255) / 256, 256, 0, stream>>>(Wq, AqT);
    k_prep_wT<<<(27 * 40 * 320 + 255) / 256, 256, 0, stream>>>(Wk, BkT);
    // M = Wq @ Wk^T via MFMA, batched over 27 (b,t)
    gemm_kernel<<<dim3(3, 3, 27), 256, 0, stream>>>(AqT, 320, BkT, nullptr,
        Mb, nullptr, 320, 320, 320, 320, 40, 0, 102400, 102400, 102400);
    k_prep_qkvW<<<(27 * 40 * NPQ + 255) / 256, 256, 0, stream>>>(Mb, BstQkv);
    k_prep_ext<<<dim3(27, 11), 256, 0, stream>>>(Wq, bq, We, be, bk, BstQkv, biasQkv);
    k_prep_qkvB<<<(27 * NPQ + 255) / 256, 256, 0, stream>>>(Wk, bq, biasQkv);
    k_prep_skipB<<<(3 * 384 + 255) / 256, 256, 0, stream>>>(bs, biasSkip);
    k_prep_bigB<<<(3 * BIGCH * 384 + 255) / 256, 256, 0, stream>>>(Ws, Wv, We, be, bv, BstBig);
    k_prep_w1W<<<(320 * 128 + 255) / 256, 256, 0, stream>>>(W1, BstW1);

    // CSR
    k_csr_zero<<<(NTYP * NPAD + 255) / 256, 256, 0, stream>>>(cnt);
    k_csr_count<<<(NTYP * N_EDGE + 255) / 256, 256, 0, stream>>>(eidx, cnt);
    k_csr_scan1<<<dim3(BPT, NTYP), 1024, 0, stream>>>(cnt, rowStart, blockSum);
    k_csr_scan2<<<1, 64, 0, stream>>>(blockSum);
    k_csr_scan3<<<(NTYP * NPAD + 255) / 256, 256, 0, stream>>>(rowStart, blockSum, cnt);
    k_csr_scatter<<<(NTYP * N_EDGE + 255) / 256, 256, 0, stream>>>(eidx, cnt, sSrc, sEid);

    const int mt = (N_NODES + 127) / 128;  // 391
    const int et = (N_EDGE + 255) / 256;
    // Anodes = x @ [W1a|W1b]
    gemm_kernel<<<dim3(1, mt), 256, 0, stream>>>(hAg, N_NODES, BstW1, nullptr,
        Anodes, nullptr, 64, 64, N_NODES, 128, 40, 0, 0, 0, 0);
    if (bigEa) {
        for (int t = 0; t < NTYP; ++t)
            k_edge_mlp<<<dim3(et), 256, 0, stream>>>(
                Anodes, eidx, eattr, W1, b1, W2, b2, newEa + (size_t)t * N_EDGE * EH, t);
    }

    for (int b = 0; b < NBLK; ++b) {
        for (int t = 0; t < NTYP; ++t) {
            int bt = b * NTYP + t;
            u16* eaT = bigEa ? (newEa + (size_t)t * N_EDGE * EH) : newEa;
            if (!bigEa)
                k_edge_mlp<<<dim3(et), 256, 0, stream>>>(
                    Anodes, eidx, eattr, W1, b1, W2, b2, eaT, t);
            gemm_kernel<<<dim3(3, mt), 256, 0, stream>>>(
                hAg, N_NODES, BstQkv + (size_t)bt * 40 * NPQ * 8, biasQkv + bt * NPQ,
                qkv, nullptr, QLD, QCOLS, N_NODES, NPQ, 40, 0, 0, 0, 0);
            k_attn<<<dim3(N_NODES / 4), 256, 0, stream>>>(
                qkv, hNode, rowStart + t * NPAD, sSrc + (size_t)t * N_EDGE,
                sEid + (size_t)t * N_EDGE, eaT, hAg, 40 + (t % nslots) * 45);
            if (nslots == 2) {
                if (t & 1) {  // groups of 2 types
                    int g = t >> 1;
                    const int gOff2[4] = {0, 130, 220, 310};
                    const int gKQ2[4]  = {132, 92, 92, 92};
                    gemm_kernel<<<dim3(3, mt), 256, 0, stream>>>(
                        (g == 0) ? hAg : regionB, N_NODES,
                        BstBig + ((size_t)b * BIGCH + gOff2[g]) * 384 * 8,
                        (g == 0) ? (biasSkip + b * 384) : nullptr,
                        nullptr, acc, DIM, DIM, N_NODES, 384, gKQ2[g],
                        (g == 0) ? 1 : 2, 0, 0, 0);
                }
            } else {
                if (t == 3)       // g0: h + t0..t3, K=220 chunks, mode 1
                    gemm_kernel<<<dim3(3, mt), 256, 0, stream>>>(
                        hAg, N_NODES, BstBig + (size_t)b * BIGCH * 384 * 8,
                        biasSkip + b * 384, nullptr, acc, DIM, DIM, N_NODES,
                        384, 220, 1, 0, 0, 0);
                else if (t == 7)  // g1: t4..t7, K=180 chunks, mode 2
                    gemm_kernel<<<dim3(3, mt), 256, 0, stream>>>(
                        regionB, N_NODES, BstBig + ((size_t)b * BIGCH + 220) * 384 * 8,
                        nullptr, nullptr, acc, DIM, DIM, N_NODES,
                        384, 180, 2, 0, 0, 0);
            }
        }
        // final group: type 8 alone (slot 0); A tail reads 3 stale chunks of
        // slot 1, B chunks 445-447 are zero -> contributes 0
        gemm_kernel<<<dim3(3, mt), 256, 0, stream>>>(
            regionB, N_NODES, BstBig + ((size_t)b * BIGCH + 400) * 384 * 8, nullptr,
            nullptr, acc, DIM, DIM, N_NODES, 384, 48, 2, 0, 0, 0);
        k_post<<<N_GRAPH, 1024, 0, stream>>>(acc, hAg, hNode, batch,
                                             gamma + b * DIM, beta + b * DIM);
    }
    k_maxpool<<<N_GRAPH, 320, 0, stream>>>(hAg, batch, out);
}